// Round 2
// baseline (4135.638 us; speedup 1.0000x reference)
//
#include <hip/hip_runtime.h>

// Problem constants
constexpr int N_SITE    = 100000;
constexpr int N_VENDOR  = 20000;
constexpr int NE        = 3200000;
constexpr int SITE_IN   = 10;
constexpr int VENDOR_IN = 9;
constexpr int HID       = 64;
constexpr int OUT       = 32;

// Workspace layout (float offsets). Zone [0, OFF_ZEROEND) is zeroed each call.
constexpr long long OFF_CNT_V   = 0;                                           // [20000]
constexpr long long OFF_CNT_S   = OFF_CNT_V   + N_VENDOR;                      // [100000]
constexpr long long OFF_AGG_V10 = OFF_CNT_S   + N_SITE;                        // [20000*10]
constexpr long long OFF_AGG_S9  = OFF_AGG_V10 + (long long)N_VENDOR * SITE_IN; // [100000*9]
constexpr long long OFF_AGG_V32 = OFF_AGG_S9  + (long long)N_SITE * VENDOR_IN; // [20000*32]
constexpr long long OFF_AGG_S32 = OFF_AGG_V32 + (long long)N_VENDOR * OUT;     // [100000*32]
constexpr long long OFF_ZEROEND = OFF_AGG_S32 + (long long)N_SITE * OUT;
constexpr long long OFF_XS1     = OFF_ZEROEND;                                 // [100000*64]
constexpr long long OFF_XV1     = OFF_XS1 + (long long)N_SITE * HID;           // [20000*64]
constexpr long long OFF_FUSED   = OFF_XV1 + (long long)N_VENDOR * HID;         // [2688]
constexpr long long WS_FLOATS   = OFF_FUSED + 2688;
// ys/yv (layer-2 pre-projections) live in d_out: ys = out[0:N_SITE*32],
// yv = out[N_SITE*32:]; both are dead before combine2 overwrites d_out.

// fused sub-offsets
constexpr int F_M1SV = 0;     // 10x64  W_site_in@Wl1sv
constexpr int F_V1SV = 640;   // 64     b_site_in@Wl1sv
constexpr int F_M1VS = 704;   // 9x64   W_vendor_in@Wl1vs
constexpr int F_V1VS = 1280;  // 64     b_vendor_in@Wl1vs
constexpr int F_R1SV = 1344;  // 9x64   W_vendor_in@Wr1sv  (vendor self term)
constexpr int F_r1SV = 1920;  // 64     b_vendor_in@Wr1sv
constexpr int F_R1VS = 1984;  // 10x64  W_site_in@Wr1vs    (site self term)
constexpr int F_r1VS = 2624;  // 64     b_site_in@Wr1vs

// ---------------------------------------------------------------------------
// Fold input projection + layer-1 weights into tiny fused matrices.
__global__ void fuse_weights(const float* __restrict__ Wsi, const float* __restrict__ bsi,
                             const float* __restrict__ Wvi, const float* __restrict__ bvi,
                             const float* __restrict__ Wl1sv, const float* __restrict__ Wr1sv,
                             const float* __restrict__ Wl1vs, const float* __restrict__ Wr1vs,
                             float* __restrict__ fused) {
    int idx = blockIdx.x * blockDim.x + threadIdx.x;
    float* M1sv = fused + F_M1SV; float* v1sv = fused + F_V1SV;
    float* M1vs = fused + F_M1VS; float* v1vs = fused + F_V1VS;
    float* R1sv = fused + F_R1SV; float* r1sv = fused + F_r1SV;
    float* R1vs = fused + F_R1VS; float* r1vs = fused + F_r1VS;
    if (idx < 640) { int k = idx >> 6, c = idx & 63; float s = 0.f;
        for (int j = 0; j < 64; ++j) s = fmaf(Wsi[k*64+j], Wl1sv[j*64+c], s);
        M1sv[idx] = s; return; }
    idx -= 640;
    if (idx < 64) { float s = 0.f;
        for (int j = 0; j < 64; ++j) s = fmaf(bsi[j], Wl1sv[j*64+idx], s);
        v1sv[idx] = s; return; }
    idx -= 64;
    if (idx < 576) { int k = idx / 64, c = idx & 63; float s = 0.f;
        for (int j = 0; j < 64; ++j) s = fmaf(Wvi[k*64+j], Wl1vs[j*64+c], s);
        M1vs[idx] = s; return; }
    idx -= 576;
    if (idx < 64) { float s = 0.f;
        for (int j = 0; j < 64; ++j) s = fmaf(bvi[j], Wl1vs[j*64+idx], s);
        v1vs[idx] = s; return; }
    idx -= 64;
    if (idx < 576) { int k = idx / 64, c = idx & 63; float s = 0.f;
        for (int j = 0; j < 64; ++j) s = fmaf(Wvi[k*64+j], Wr1sv[j*64+c], s);
        R1sv[idx] = s; return; }
    idx -= 576;
    if (idx < 64) { float s = 0.f;
        for (int j = 0; j < 64; ++j) s = fmaf(bvi[j], Wr1sv[j*64+idx], s);
        r1sv[idx] = s; return; }
    idx -= 64;
    if (idx < 640) { int k = idx >> 6, c = idx & 63; float s = 0.f;
        for (int j = 0; j < 64; ++j) s = fmaf(Wsi[k*64+j], Wr1vs[j*64+c], s);
        R1vs[idx] = s; return; }
    idx -= 640;
    if (idx < 64) { float s = 0.f;
        for (int j = 0; j < 64; ++j) s = fmaf(bsi[j], Wr1vs[j*64+idx], s);
        r1vs[idx] = s; return; }
}

// ---------------------------------------------------------------------------
// Layer-1 aggregation on RAW features (10-dim site rows, 9-dim vendor rows)
// plus degree counts. One thread per edge.
__global__ __launch_bounds__(256) void agg1(const float* __restrict__ x_site,
                                            const float* __restrict__ x_vendor,
                                            const int* __restrict__ src,
                                            const int* __restrict__ dst,
                                            float* __restrict__ agg_v10,
                                            float* __restrict__ agg_s9,
                                            float* __restrict__ cnt_v,
                                            float* __restrict__ cnt_s) {
    int e = blockIdx.x * blockDim.x + threadIdx.x;
    if (e >= NE) return;
    int s = src[e], d = dst[e];
    const float* xr = x_site + (long long)s * SITE_IN;
    float* av = agg_v10 + (long long)d * SITE_IN;
    #pragma unroll
    for (int f = 0; f < SITE_IN; ++f) atomicAdd(&av[f], xr[f]);
    const float* vr = x_vendor + (long long)d * VENDOR_IN;
    float* as = agg_s9 + (long long)s * VENDOR_IN;
    #pragma unroll
    for (int f = 0; f < VENDOR_IN; ++f) atomicAdd(&as[f], vr[f]);
    atomicAdd(&cnt_v[d], 1.0f);
    atomicAdd(&cnt_s[s], 1.0f);
}

// ---------------------------------------------------------------------------
// Layer-1 combine: x1 = relu( (agg/max(cnt,1)) @ M + [cnt>0]*v + bl + xself @ R + r )
// KA = aggregated raw feature dim, KX = self raw feature dim. 1 thread/output.
template<int KA, int KX>
__global__ __launch_bounds__(256) void combine1_k(const float* __restrict__ xself,
                                                  const float* __restrict__ agg,
                                                  const float* __restrict__ cnt,
                                                  const float* __restrict__ M,
                                                  const float* __restrict__ v,
                                                  const float* __restrict__ bl,
                                                  const float* __restrict__ R,
                                                  const float* __restrict__ r,
                                                  float* __restrict__ x1, int n) {
    __shared__ float sM[KA * 64];
    __shared__ float sR[KX * 64];
    __shared__ float sv[64], sb[64], sr[64];
    for (int i = threadIdx.x; i < KA * 64; i += 256) sM[i] = M[i];
    for (int i = threadIdx.x; i < KX * 64; i += 256) sR[i] = R[i];
    if (threadIdx.x < 64) {
        sv[threadIdx.x] = v[threadIdx.x];
        sb[threadIdx.x] = bl[threadIdx.x];
        sr[threadIdx.x] = r[threadIdx.x];
    }
    __syncthreads();
    int idx = blockIdx.x * 256 + threadIdx.x;
    if (idx >= n * HID) return;
    int i = idx >> 6, c = idx & 63;
    float cv = cnt[i];
    float inv = 1.0f / fmaxf(cv, 1.0f);
    float acc = sb[c] + sr[c] + (cv > 0.0f ? sv[c] : 0.0f);
    const float* ar = agg + (long long)i * KA;
    #pragma unroll
    for (int k = 0; k < KA; ++k) acc = fmaf(ar[k] * inv, sM[k * 64 + c], acc);
    const float* xr = xself + (long long)i * KX;
    #pragma unroll
    for (int k = 0; k < KX; ++k) acc = fmaf(xr[k], sR[k * 64 + c], acc);
    x1[idx] = fmaxf(acc, 0.0f);
}

// ---------------------------------------------------------------------------
// Y[n,32] = X[n,64] @ W[64,32]  (pre-projection for layer-2 aggregation)
__global__ __launch_bounds__(256) void proj32(const float* __restrict__ X,
                                              const float* __restrict__ W,
                                              float* __restrict__ Y, int n) {
    __shared__ float sW[64 * 32];
    for (int i = threadIdx.x; i < 64 * 32; i += 256) sW[i] = W[i];
    __syncthreads();
    int idx = blockIdx.x * 256 + threadIdx.x;
    if (idx >= n * 32) return;
    int i = idx >> 5, c = idx & 31;
    const float* xr = X + (long long)i * 64;
    float acc = 0.f;
    #pragma unroll
    for (int k = 0; k < 64; ++k) acc = fmaf(xr[k], sW[k * 32 + c], acc);
    Y[idx] = acc;
}

// ---------------------------------------------------------------------------
// Layer-2 aggregation of pre-projected 32-dim rows; 32 lanes per edge so the
// 128B row gather + scatter-atomics are coalesced.
__global__ __launch_bounds__(256) void agg2(const int* __restrict__ src,
                                            const int* __restrict__ dst,
                                            const float* __restrict__ ys,
                                            const float* __restrict__ yv,
                                            float* __restrict__ agg_v32,
                                            float* __restrict__ agg_s32) {
    int t = blockIdx.x * 256 + threadIdx.x;
    int e = t >> 5;
    if (e >= NE) return;
    int f = t & 31;
    int s = src[e], d = dst[e];
    atomicAdd(&agg_v32[(long long)d * 32 + f], ys[(long long)s * 32 + f]);
    atomicAdd(&agg_s32[(long long)s * 32 + f], yv[(long long)d * 32 + f]);
}

// ---------------------------------------------------------------------------
// Layer-2 combine: out = relu( agg/max(cnt,1) + b + X @ Wr )
__global__ __launch_bounds__(256) void combine2_k(const float* __restrict__ agg,
                                                  const float* __restrict__ cnt,
                                                  const float* __restrict__ X,
                                                  const float* __restrict__ Wr,
                                                  const float* __restrict__ b,
                                                  float* __restrict__ out, int n) {
    __shared__ float sW[64 * 32];
    __shared__ float sb[32];
    for (int i = threadIdx.x; i < 64 * 32; i += 256) sW[i] = Wr[i];
    if (threadIdx.x < 32) sb[threadIdx.x] = b[threadIdx.x];
    __syncthreads();
    int idx = blockIdx.x * 256 + threadIdx.x;
    if (idx >= n * 32) return;
    int i = idx >> 5, c = idx & 31;
    float cv = cnt[i];
    float inv = 1.0f / fmaxf(cv, 1.0f);
    float acc = agg[idx] * inv + sb[c];
    const float* xr = X + (long long)i * 64;
    #pragma unroll
    for (int k = 0; k < 64; ++k) acc = fmaf(xr[k], sW[k * 32 + c], acc);
    out[idx] = fmaxf(acc, 0.0f);
}

// ---------------------------------------------------------------------------
extern "C" void kernel_launch(void* const* d_in, const int* in_sizes, int n_in,
                              void* d_out, int out_size, void* d_ws, size_t ws_size,
                              hipStream_t stream) {
    const float* x_site      = (const float*)d_in[0];
    const float* x_vendor    = (const float*)d_in[1];
    const int*   src         = (const int*)d_in[2];
    const int*   dst         = (const int*)d_in[3];
    const float* W_site_in   = (const float*)d_in[4];
    const float* b_site_in   = (const float*)d_in[5];
    const float* W_vendor_in = (const float*)d_in[6];
    const float* b_vendor_in = (const float*)d_in[7];
    const float* Wl1sv = (const float*)d_in[8];
    const float* bl1sv = (const float*)d_in[9];
    const float* Wr1sv = (const float*)d_in[10];
    const float* Wl1vs = (const float*)d_in[11];
    const float* bl1vs = (const float*)d_in[12];
    const float* Wr1vs = (const float*)d_in[13];
    const float* Wl2sv = (const float*)d_in[14];
    const float* bl2sv = (const float*)d_in[15];
    const float* Wr2sv = (const float*)d_in[16];
    const float* Wl2vs = (const float*)d_in[17];
    const float* bl2vs = (const float*)d_in[18];
    const float* Wr2vs = (const float*)d_in[19];

    // Guard: never write past the harness scratch (a silent overrun here can
    // fault the GPU and kill the container; a clean early-return just fails
    // validation and tells us to shrink the footprint).
    if (ws_size < (size_t)WS_FLOATS * sizeof(float)) return;

    float* ws  = (float*)d_ws;
    float* out = (float*)d_out;

    float* cnt_v   = ws + OFF_CNT_V;
    float* cnt_s   = ws + OFF_CNT_S;
    float* agg_v10 = ws + OFF_AGG_V10;
    float* agg_s9  = ws + OFF_AGG_S9;
    float* agg_v32 = ws + OFF_AGG_V32;
    float* agg_s32 = ws + OFF_AGG_S32;
    float* xs1     = ws + OFF_XS1;
    float* xv1     = ws + OFF_XV1;
    float* fused   = ws + OFF_FUSED;
    // layer-2 pre-projections live in d_out (dead before combine2 overwrites it)
    float* ys = out;                              // [N_SITE * 32]
    float* yv = out + (long long)N_SITE * OUT;    // [N_VENDOR * 32]

    // zero the accumulators (ws is NOT re-poisoned between replays; zero every call)
    hipMemsetAsync(ws, 0, (size_t)OFF_ZEROEND * sizeof(float), stream);

    fuse_weights<<<11, 256, 0, stream>>>(W_site_in, b_site_in, W_vendor_in, b_vendor_in,
                                         Wl1sv, Wr1sv, Wl1vs, Wr1vs, fused);

    agg1<<<(NE + 255) / 256, 256, 0, stream>>>(x_site, x_vendor, src, dst,
                                               agg_v10, agg_s9, cnt_v, cnt_s);

    // xs1 = relu(mean_s(xv)@Wl1vs + bl1vs + xs@Wr1vs)   [100000 x 64]
    combine1_k<VENDOR_IN, SITE_IN><<<(N_SITE * HID + 255) / 256, 256, 0, stream>>>(
        x_site, agg_s9, cnt_s,
        fused + F_M1VS, fused + F_V1VS, bl1vs, fused + F_R1VS, fused + F_r1VS,
        xs1, N_SITE);
    // xv1 = relu(mean_v(xs)@Wl1sv + bl1sv + xv@Wr1sv)   [20000 x 64]
    combine1_k<SITE_IN, VENDOR_IN><<<(N_VENDOR * HID + 255) / 256, 256, 0, stream>>>(
        x_vendor, agg_v10, cnt_v,
        fused + F_M1SV, fused + F_V1SV, bl1sv, fused + F_R1SV, fused + F_r1SV,
        xv1, N_VENDOR);

    // pre-projections for layer 2 (into d_out scratch)
    proj32<<<(N_SITE * 32 + 255) / 256, 256, 0, stream>>>(xs1, Wl2sv, ys, N_SITE);
    proj32<<<(N_VENDOR * 32 + 255) / 256, 256, 0, stream>>>(xv1, Wl2vs, yv, N_VENDOR);

    agg2<<<(int)(((long long)NE * 32 + 255) / 256), 256, 0, stream>>>(src, dst, ys, yv,
                                                                      agg_v32, agg_s32);

    // xs2 -> out[0 : N_SITE*32]
    combine2_k<<<(N_SITE * 32 + 255) / 256, 256, 0, stream>>>(
        agg_s32, cnt_s, xs1, Wr2vs, bl2vs, out, N_SITE);
    // xv2 -> out[N_SITE*32 : ]
    combine2_k<<<(N_VENDOR * 32 + 255) / 256, 256, 0, stream>>>(
        agg_v32, cnt_v, xv1, Wr2sv, bl2sv, out + (long long)N_SITE * OUT, N_VENDOR);

    (void)in_sizes; (void)n_in; (void)out_size;
}

// Round 3
// 1605.105 us; speedup vs baseline: 2.5766x; 2.5766x over previous
//
#include <hip/hip_runtime.h>

// Problem constants
constexpr int N_SITE    = 100000;
constexpr int N_VENDOR  = 20000;
constexpr int NE        = 3200000;
constexpr int SITE_IN   = 10;
constexpr int VENDOR_IN = 9;
constexpr int HID       = 64;
constexpr int OUT       = 32;
constexpr int SEGSZ     = 12500;   // LDS histogram segment (50 KB of int32)

// ---------------------------------------------------------------------------
// Workspace layout. All slots are 4-byte words; int region first, then floats.
constexpr long long I_CUR_V = 0;                          // [20000]  hist -> cursor
constexpr long long I_CUR_S = I_CUR_V + N_VENDOR;         // [100000]
constexpr long long I_OFF_V = I_CUR_S + N_SITE;           // [20001]  immutable offsets
constexpr long long I_OFF_S = I_OFF_V + N_VENDOR + 1;     // [100001]
constexpr long long I_ADJ_V = I_OFF_S + N_SITE + 1;       // [NE] src grouped by dst
constexpr long long I_ADJ_S = I_ADJ_V + NE;               // [NE] dst grouped by src
constexpr long long INT_END = I_ADJ_S + NE;
constexpr long long F_XS1   = INT_END;                    // [100000*64]
constexpr long long F_XV1   = F_XS1 + (long long)N_SITE * HID;    // [20000*64]
constexpr long long F_YS    = F_XV1 + (long long)N_VENDOR * HID;  // [100000*32]
constexpr long long F_YV    = F_YS  + (long long)N_SITE * OUT;    // [20000*32]
constexpr long long F_FUSED = F_YV  + (long long)N_VENDOR * OUT;  // [2688]
constexpr long long WS_WORDS = F_FUSED + 2688;            // ~72.7 MB

// fused sub-offsets
constexpr int F_M1SV = 0;     // 10x64  W_site_in@Wl1sv
constexpr int F_V1SV = 640;   // 64     b_site_in@Wl1sv
constexpr int F_M1VS = 704;   // 9x64   W_vendor_in@Wl1vs
constexpr int F_V1VS = 1280;  // 64     b_vendor_in@Wl1vs
constexpr int F_R1SV = 1344;  // 9x64   W_vendor_in@Wr1sv  (vendor self term)
constexpr int F_r1SV = 1920;  // 64     b_vendor_in@Wr1sv
constexpr int F_R1VS = 1984;  // 10x64  W_site_in@Wr1vs    (site self term)
constexpr int F_r1VS = 2624;  // 64     b_site_in@Wr1vs

// ---------------------------------------------------------------------------
// Fold input projection + layer-1 weights into tiny fused matrices.
__global__ void fuse_weights(const float* __restrict__ Wsi, const float* __restrict__ bsi,
                             const float* __restrict__ Wvi, const float* __restrict__ bvi,
                             const float* __restrict__ Wl1sv, const float* __restrict__ Wr1sv,
                             const float* __restrict__ Wl1vs, const float* __restrict__ Wr1vs,
                             float* __restrict__ fused) {
    int idx = blockIdx.x * blockDim.x + threadIdx.x;
    if (idx < 640) { int k = idx >> 6, c = idx & 63; float s = 0.f;
        for (int j = 0; j < 64; ++j) s = fmaf(Wsi[k*64+j], Wl1sv[j*64+c], s);
        fused[F_M1SV + idx] = s; return; }
    idx -= 640;
    if (idx < 64) { float s = 0.f;
        for (int j = 0; j < 64; ++j) s = fmaf(bsi[j], Wl1sv[j*64+idx], s);
        fused[F_V1SV + idx] = s; return; }
    idx -= 64;
    if (idx < 576) { int k = idx / 64, c = idx & 63; float s = 0.f;
        for (int j = 0; j < 64; ++j) s = fmaf(Wvi[k*64+j], Wl1vs[j*64+c], s);
        fused[F_M1VS + idx] = s; return; }
    idx -= 576;
    if (idx < 64) { float s = 0.f;
        for (int j = 0; j < 64; ++j) s = fmaf(bvi[j], Wl1vs[j*64+idx], s);
        fused[F_V1VS + idx] = s; return; }
    idx -= 64;
    if (idx < 576) { int k = idx / 64, c = idx & 63; float s = 0.f;
        for (int j = 0; j < 64; ++j) s = fmaf(Wvi[k*64+j], Wr1sv[j*64+c], s);
        fused[F_R1SV + idx] = s; return; }
    idx -= 576;
    if (idx < 64) { float s = 0.f;
        for (int j = 0; j < 64; ++j) s = fmaf(bvi[j], Wr1sv[j*64+idx], s);
        fused[F_r1SV + idx] = s; return; }
    idx -= 64;
    if (idx < 640) { int k = idx >> 6, c = idx & 63; float s = 0.f;
        for (int j = 0; j < 64; ++j) s = fmaf(Wsi[k*64+j], Wr1vs[j*64+c], s);
        fused[F_R1VS + idx] = s; return; }
    idx -= 640;
    if (idx < 64) { float s = 0.f;
        for (int j = 0; j < 64; ++j) s = fmaf(bsi[j], Wr1vs[j*64+idx], s);
        fused[F_r1VS + idx] = s; return; }
}

// ---------------------------------------------------------------------------
// LDS-privatized histogram. grid = (chunks, segments). deg must be pre-zeroed.
__global__ __launch_bounds__(256) void histk(const int* __restrict__ idx, int nedge,
                                             int* __restrict__ deg, int nbins) {
    __shared__ int h[SEGSZ];
    int seg_lo = blockIdx.y * SEGSZ;
    for (int i = threadIdx.x; i < SEGSZ; i += 256) h[i] = 0;
    __syncthreads();
    int per = (nedge + gridDim.x - 1) / gridDim.x;
    int lo = blockIdx.x * per, hi = min(lo + per, nedge);
    for (int e = lo + threadIdx.x; e < hi; e += 256) {
        int v = idx[e] - seg_lo;
        if ((unsigned)v < (unsigned)SEGSZ) atomicAdd(&h[v], 1);
    }
    __syncthreads();
    for (int i = threadIdx.x; i < SEGSZ; i += 256) {
        int b = seg_lo + i;
        if (b < nbins && h[i]) atomicAdd(&deg[b], h[i]);  // coalesced merge
    }
}

// ---------------------------------------------------------------------------
// Single-block exclusive scan: reads deg (in `cur`), writes off[i]=prefix,
// off[n]=total, and rewrites cur[i]=prefix (fill cursors). 1024 threads.
__global__ __launch_bounds__(1024) void scank(int* __restrict__ cur,
                                              int* __restrict__ off, int n) {
    __shared__ int part[1024];
    int tid = threadIdx.x;
    int per = (n + 1023) / 1024;
    int lo = tid * per, hi = min(lo + per, n);
    int s = 0;
    for (int i = lo; i < hi; ++i) s += cur[i];
    part[tid] = s;
    __syncthreads();
    for (int st = 1; st < 1024; st <<= 1) {
        int v = (tid >= st) ? part[tid - st] : 0;
        __syncthreads();
        part[tid] += v;
        __syncthreads();
    }
    int run = (tid == 0) ? 0 : part[tid - 1];
    for (int i = lo; i < hi; ++i) {
        int t = cur[i];
        off[i] = run;
        cur[i] = run;
        run += t;
    }
    if (lo < n && hi == n) off[n] = run;
}

// ---------------------------------------------------------------------------
// LDS-privatized CSR fill. Pass 1: local hist. Merge: one coalesced global
// atomicAdd per (block,bin) reserves a range; returned base overwrites the
// LDS slot. Pass 2: LDS atomicAdd hands out exact global positions.
__global__ __launch_bounds__(256) void fillk(const int* __restrict__ key,
                                             const int* __restrict__ val,
                                             int nedge, int* __restrict__ cur,
                                             int* __restrict__ adj, int nbins) {
    __shared__ int h[SEGSZ];
    int seg_lo = blockIdx.y * SEGSZ;
    for (int i = threadIdx.x; i < SEGSZ; i += 256) h[i] = 0;
    __syncthreads();
    int per = (nedge + gridDim.x - 1) / gridDim.x;
    int lo = blockIdx.x * per, hi = min(lo + per, nedge);
    for (int e = lo + threadIdx.x; e < hi; e += 256) {
        int v = key[e] - seg_lo;
        if ((unsigned)v < (unsigned)SEGSZ) atomicAdd(&h[v], 1);
    }
    __syncthreads();
    for (int i = threadIdx.x; i < SEGSZ; i += 256) {
        int b = seg_lo + i;
        if (b < nbins) {
            int c = h[i];
            h[i] = c ? atomicAdd(&cur[b], c) : 0;   // base of this block's range
        }
    }
    __syncthreads();
    for (int e = lo + threadIdx.x; e < hi; e += 256) {
        int v = key[e] - seg_lo;
        if ((unsigned)v < (unsigned)SEGSZ) {
            int p = atomicAdd(&h[v], 1);
            adj[p] = val[e];
        }
    }
}

// ---------------------------------------------------------------------------
// Fused layer-1: per-node gather of KA-dim raw neighbor rows + mean-project
// + self-project + biases + relu. One wave (64 lanes) per node.
// x1[i][c] = relu( mean_k @ M + [deg>0]*v + bl + xself_k @ R + r )
template<int KA, int KX>
__global__ __launch_bounds__(256) void gc1(const float* __restrict__ feat_src,
                                           const float* __restrict__ feat_self,
                                           const int* __restrict__ off,
                                           const int* __restrict__ adj,
                                           const float* __restrict__ M,
                                           const float* __restrict__ v64,
                                           const float* __restrict__ bl,
                                           const float* __restrict__ R,
                                           const float* __restrict__ rvec,
                                           float* __restrict__ x1, int n) {
    int w = (blockIdx.x * 256 + threadIdx.x) >> 6;
    int lane = threadIdx.x & 63;
    if (w >= n) return;
    int lo = off[w], hi = off[w + 1];
    int deg = hi - lo;
    float s[KA];
    #pragma unroll
    for (int k = 0; k < KA; ++k) s[k] = 0.f;
    for (int j = lo + lane; j < hi; j += 64) {
        const float* fr = feat_src + (long long)adj[j] * KA;
        #pragma unroll
        for (int k = 0; k < KA; ++k) s[k] += fr[k];
    }
    #pragma unroll
    for (int k = 0; k < KA; ++k) {
        #pragma unroll
        for (int m = 32; m >= 1; m >>= 1) s[k] += __shfl_xor(s[k], m, 64);
    }
    float inv = 1.0f / (float)max(deg, 1);
    float acc = bl[lane] + rvec[lane] + (deg > 0 ? v64[lane] : 0.f);
    #pragma unroll
    for (int k = 0; k < KA; ++k) acc = fmaf(s[k] * inv, M[k * 64 + lane], acc);
    const float* xr = feat_self + (long long)w * KX;
    #pragma unroll
    for (int k = 0; k < KX; ++k) acc = fmaf(xr[k], R[k * 64 + lane], acc);
    x1[(long long)w * 64 + lane] = fmaxf(acc, 0.f);
}

// ---------------------------------------------------------------------------
// Y[n,32] = X[n,64] @ W[64,32]  (pre-projection for layer-2 aggregation)
__global__ __launch_bounds__(256) void proj32(const float* __restrict__ X,
                                              const float* __restrict__ W,
                                              float* __restrict__ Y, int n) {
    __shared__ float sW[64 * 32];
    for (int i = threadIdx.x; i < 64 * 32; i += 256) sW[i] = W[i];
    __syncthreads();
    int idx = blockIdx.x * 256 + threadIdx.x;
    if (idx >= n * 32) return;
    int i = idx >> 5, c = idx & 31;
    const float* xr = X + (long long)i * 64;
    float acc = 0.f;
    #pragma unroll
    for (int k = 0; k < 64; ++k) acc = fmaf(xr[k], sW[k * 32 + c], acc);
    Y[idx] = acc;
}

// ---------------------------------------------------------------------------
// Fused layer-2: per-node gather of 32-dim pre-projected rows + mean + bias
// + self(64)@Wr + relu. One wave per node; lanes = 2 edges x 32 cols.
__global__ __launch_bounds__(256) void gc2(const float* __restrict__ y,
                                           const float* __restrict__ Xself,
                                           const int* __restrict__ off,
                                           const int* __restrict__ adj,
                                           const float* __restrict__ Wr,
                                           const float* __restrict__ b,
                                           float* __restrict__ outp, int n) {
    int w = (blockIdx.x * 256 + threadIdx.x) >> 6;
    int lane = threadIdx.x & 63;
    if (w >= n) return;
    int c = lane & 31, g = lane >> 5;
    int lo = off[w], hi = off[w + 1];
    int deg = hi - lo;
    float s = 0.f;
    for (int j = lo + g; j < hi; j += 2)
        s += y[(long long)adj[j] * 32 + c];
    s += __shfl_xor(s, 32, 64);
    float inv = 1.0f / (float)max(deg, 1);
    float acc = s * inv + b[c];
    const float* xr = Xself + (long long)w * 64;
    #pragma unroll
    for (int k = 0; k < 64; ++k) acc = fmaf(xr[k], Wr[k * 32 + c], acc);
    if (g == 0) outp[(long long)w * 32 + c] = fmaxf(acc, 0.f);
}

// ---------------------------------------------------------------------------
extern "C" void kernel_launch(void* const* d_in, const int* in_sizes, int n_in,
                              void* d_out, int out_size, void* d_ws, size_t ws_size,
                              hipStream_t stream) {
    const float* x_site      = (const float*)d_in[0];
    const float* x_vendor    = (const float*)d_in[1];
    const int*   src         = (const int*)d_in[2];
    const int*   dst         = (const int*)d_in[3];
    const float* W_site_in   = (const float*)d_in[4];
    const float* b_site_in   = (const float*)d_in[5];
    const float* W_vendor_in = (const float*)d_in[6];
    const float* b_vendor_in = (const float*)d_in[7];
    const float* Wl1sv = (const float*)d_in[8];
    const float* bl1sv = (const float*)d_in[9];
    const float* Wr1sv = (const float*)d_in[10];
    const float* Wl1vs = (const float*)d_in[11];
    const float* bl1vs = (const float*)d_in[12];
    const float* Wr1vs = (const float*)d_in[13];
    const float* Wl2sv = (const float*)d_in[14];
    const float* bl2sv = (const float*)d_in[15];
    const float* Wr2sv = (const float*)d_in[16];
    const float* Wl2vs = (const float*)d_in[17];
    const float* bl2vs = (const float*)d_in[18];
    const float* Wr2vs = (const float*)d_in[19];

    // Guard: never write past harness scratch (overrun can kill the container).
    if (ws_size < (size_t)WS_WORDS * 4) return;

    int*   wi  = (int*)d_ws;
    float* wf  = (float*)d_ws;
    float* out = (float*)d_out;

    int* cur_v = wi + I_CUR_V;
    int* cur_s = wi + I_CUR_S;
    int* off_v = wi + I_OFF_V;
    int* off_s = wi + I_OFF_S;
    int* adj_v = wi + I_ADJ_V;
    int* adj_s = wi + I_ADJ_S;
    float* xs1   = wf + F_XS1;
    float* xv1   = wf + F_XV1;
    float* ys    = wf + F_YS;
    float* yv    = wf + F_YV;
    float* fused = wf + F_FUSED;

    // zero the histogram accumulators (ws not re-poisoned between replays)
    hipMemsetAsync(wi, 0, (size_t)(N_VENDOR + N_SITE) * sizeof(int), stream);

    fuse_weights<<<11, 256, 0, stream>>>(W_site_in, b_site_in, W_vendor_in, b_vendor_in,
                                         Wl1sv, Wr1sv, Wl1vs, Wr1vs, fused);

    // degree histograms (LDS-privatized)
    histk<<<dim3(32, 2), 256, 0, stream>>>(dst, NE, cur_v, N_VENDOR);
    histk<<<dim3(32, 8), 256, 0, stream>>>(src, NE, cur_s, N_SITE);

    // exclusive scans -> offsets + cursors
    scank<<<1, 1024, 0, stream>>>(cur_v, off_v, N_VENDOR);
    scank<<<1, 1024, 0, stream>>>(cur_s, off_s, N_SITE);

    // CSR fill (both directions)
    fillk<<<dim3(32, 2), 256, 0, stream>>>(dst, src, NE, cur_v, adj_v, N_VENDOR);
    fillk<<<dim3(32, 8), 256, 0, stream>>>(src, dst, NE, cur_s, adj_s, N_SITE);

    // layer 1 (fused gather+project+self+relu), raw-feature aggregation
    // xs1: site nodes aggregate 9-dim vendor rows
    gc1<VENDOR_IN, SITE_IN><<<(N_SITE + 3) / 4, 256, 0, stream>>>(
        x_vendor, x_site, off_s, adj_s,
        fused + F_M1VS, fused + F_V1VS, bl1vs, fused + F_R1VS, fused + F_r1VS,
        xs1, N_SITE);
    // xv1: vendor nodes aggregate 10-dim site rows
    gc1<SITE_IN, VENDOR_IN><<<(N_VENDOR + 3) / 4, 256, 0, stream>>>(
        x_site, x_vendor, off_v, adj_v,
        fused + F_M1SV, fused + F_V1SV, bl1sv, fused + F_R1SV, fused + F_r1SV,
        xv1, N_VENDOR);

    // layer-2 pre-projections
    proj32<<<(N_SITE * 32 + 255) / 256, 256, 0, stream>>>(xs1, Wl2sv, ys, N_SITE);
    proj32<<<(N_VENDOR * 32 + 255) / 256, 256, 0, stream>>>(xv1, Wl2vs, yv, N_VENDOR);

    // layer 2 (fused gather+mean+self+relu) straight into d_out
    // xv2 -> out[N_SITE*32:]
    gc2<<<(N_VENDOR + 3) / 4, 256, 0, stream>>>(ys, xv1, off_v, adj_v,
                                                Wr2sv, bl2sv,
                                                out + (long long)N_SITE * OUT, N_VENDOR);
    // xs2 -> out[0:N_SITE*32]
    gc2<<<(N_SITE + 3) / 4, 256, 0, stream>>>(yv, xs1, off_s, adj_s,
                                              Wr2vs, bl2vs, out, N_SITE);

    (void)in_sizes; (void)n_in; (void)out_size;
}

// Round 4
// 1504.314 us; speedup vs baseline: 2.7492x; 1.0670x over previous
//
#include <hip/hip_runtime.h>

// Problem constants
constexpr int N_SITE    = 100000;
constexpr int N_VENDOR  = 20000;
constexpr int NE        = 3200000;
constexpr int SITE_IN   = 10;
constexpr int VENDOR_IN = 9;
constexpr int HID       = 64;
constexpr int OUT       = 32;

// Chunked counting-sort parameters
constexpr int NCHUNK  = 32;
constexpr int NBLK    = 1024;            // build-kernel grid
constexpr int EPB     = NE / NBLK;       // 3125 edges per block
constexpr int BLK_PER_CHUNK_SHIFT = 5;   // 1024/32 = 32 blocks per chunk

// ---------------------------------------------------------------------------
// Workspace layout (4-byte words). int region first, then floats.
constexpr long long I_DEG_V = 0;                          // [20000]  degree / scan scratch
constexpr long long I_DEG_S = I_DEG_V + N_VENDOR;         // [100000]
constexpr long long I_OFF_V = I_DEG_S + N_SITE;           // [20001]  immutable offsets
constexpr long long I_OFF_S = I_OFF_V + N_VENDOR + 1;     // [100001]
constexpr long long I_ADJ_V = I_OFF_S + N_SITE + 1;       // [NE] src grouped by dst
constexpr long long I_ADJ_S = I_ADJ_V + NE;               // [NE] dst grouped by src
constexpr long long INT_END = I_ADJ_S + NE;
constexpr long long F_XS1   = INT_END;                    // [100000*64]
constexpr long long F_XV1   = F_XS1 + (long long)N_SITE * HID;    // [20000*64]
constexpr long long F_YS    = F_XV1 + (long long)N_VENDOR * HID;  // [100000*32]
constexpr long long F_YV    = F_YS  + (long long)N_SITE * OUT;    // [20000*32]
constexpr long long F_FUSED = F_YV  + (long long)N_VENDOR * OUT;  // [2688]
constexpr long long WS_WORDS = F_FUSED + 2688;            // ~72.7 MB
// hist2d tables ALIAS the xs1 region (dead until gc1, which runs after fill):
//   h2s = wi + F_XS1                 [NCHUNK * N_SITE]   = 3.2M ints
//   h2v = wi + F_XS1 + NCHUNK*N_SITE [NCHUNK * N_VENDOR] = 640K ints
constexpr long long A_H2S = F_XS1;
constexpr long long A_H2V = A_H2S + (long long)NCHUNK * N_SITE;
constexpr long long H2_WORDS = (long long)NCHUNK * (N_SITE + N_VENDOR);
static_assert(H2_WORDS <= (long long)N_SITE * HID, "hist2d must fit in xs1 alias");

// fused sub-offsets
constexpr int F_M1SV = 0;     // 10x64  W_site_in@Wl1sv
constexpr int F_V1SV = 640;   // 64     b_site_in@Wl1sv
constexpr int F_M1VS = 704;   // 9x64   W_vendor_in@Wl1vs
constexpr int F_V1VS = 1280;  // 64     b_vendor_in@Wl1vs
constexpr int F_R1SV = 1344;  // 9x64   W_vendor_in@Wr1sv  (vendor self term)
constexpr int F_r1SV = 1920;  // 64     b_vendor_in@Wr1sv
constexpr int F_R1VS = 1984;  // 10x64  W_site_in@Wr1vs    (site self term)
constexpr int F_r1VS = 2624;  // 64     b_site_in@Wr1vs

// ---------------------------------------------------------------------------
// Fold input projection + layer-1 weights into tiny fused matrices.
__global__ void fuse_weights(const float* __restrict__ Wsi, const float* __restrict__ bsi,
                             const float* __restrict__ Wvi, const float* __restrict__ bvi,
                             const float* __restrict__ Wl1sv, const float* __restrict__ Wr1sv,
                             const float* __restrict__ Wl1vs, const float* __restrict__ Wr1vs,
                             float* __restrict__ fused) {
    int idx = blockIdx.x * blockDim.x + threadIdx.x;
    if (idx < 640) { int k = idx >> 6, c = idx & 63; float s = 0.f;
        for (int j = 0; j < 64; ++j) s = fmaf(Wsi[k*64+j], Wl1sv[j*64+c], s);
        fused[F_M1SV + idx] = s; return; }
    idx -= 640;
    if (idx < 64) { float s = 0.f;
        for (int j = 0; j < 64; ++j) s = fmaf(bsi[j], Wl1sv[j*64+idx], s);
        fused[F_V1SV + idx] = s; return; }
    idx -= 64;
    if (idx < 576) { int k = idx / 64, c = idx & 63; float s = 0.f;
        for (int j = 0; j < 64; ++j) s = fmaf(Wvi[k*64+j], Wl1vs[j*64+c], s);
        fused[F_M1VS + idx] = s; return; }
    idx -= 576;
    if (idx < 64) { float s = 0.f;
        for (int j = 0; j < 64; ++j) s = fmaf(bvi[j], Wl1vs[j*64+idx], s);
        fused[F_V1VS + idx] = s; return; }
    idx -= 64;
    if (idx < 576) { int k = idx / 64, c = idx & 63; float s = 0.f;
        for (int j = 0; j < 64; ++j) s = fmaf(Wvi[k*64+j], Wr1sv[j*64+c], s);
        fused[F_R1SV + idx] = s; return; }
    idx -= 576;
    if (idx < 64) { float s = 0.f;
        for (int j = 0; j < 64; ++j) s = fmaf(bvi[j], Wr1sv[j*64+idx], s);
        fused[F_r1SV + idx] = s; return; }
    idx -= 64;
    if (idx < 640) { int k = idx >> 6, c = idx & 63; float s = 0.f;
        for (int j = 0; j < 64; ++j) s = fmaf(Wsi[k*64+j], Wr1vs[j*64+c], s);
        fused[F_R1VS + idx] = s; return; }
    idx -= 640;
    if (idx < 64) { float s = 0.f;
        for (int j = 0; j < 64; ++j) s = fmaf(bsi[j], Wr1vs[j*64+idx], s);
        fused[F_r1VS + idx] = s; return; }
}

// ---------------------------------------------------------------------------
// Pass A: per-chunk 2-D histogram for BOTH directions in one edge read.
// Per-chunk rows -> near-zero atomic contention, all L2-resident.
__global__ __launch_bounds__(256) void hist2d(const int* __restrict__ src,
                                              const int* __restrict__ dst,
                                              int* __restrict__ h2s,
                                              int* __restrict__ h2v) {
    int blk = blockIdx.x;
    int chunk = blk >> BLK_PER_CHUNK_SHIFT;
    int lo = blk * EPB, hi = lo + EPB;
    int* rs = h2s + (long long)chunk * N_SITE;
    int* rv = h2v + (long long)chunk * N_VENDOR;
    for (int e = lo + threadIdx.x; e < hi; e += 256) {
        atomicAdd(&rs[src[e]], 1);
        atomicAdd(&rv[dst[e]], 1);
    }
}

// Column sum over chunks: deg[b] = sum_c h2[c][b]. Coalesced per c-iteration.
__global__ __launch_bounds__(256) void colsum(const int* __restrict__ h2,
                                              int* __restrict__ deg, int n) {
    int b = blockIdx.x * 256 + threadIdx.x;
    if (b >= n) return;
    int s = 0;
    for (int c = 0; c < NCHUNK; ++c) s += h2[(long long)c * n + b];
    deg[b] = s;
}

// Single-block exclusive scan: off[i] = prefix(deg), off[n] = total.
__global__ __launch_bounds__(1024) void scank(int* __restrict__ deg,
                                              int* __restrict__ off, int n) {
    __shared__ int part[1024];
    int tid = threadIdx.x;
    int per = (n + 1023) / 1024;
    int lo = tid * per, hi = min(lo + per, n);
    int s = 0;
    for (int i = lo; i < hi; ++i) s += deg[i];
    part[tid] = s;
    __syncthreads();
    for (int st = 1; st < 1024; st <<= 1) {
        int v = (tid >= st) ? part[tid - st] : 0;
        __syncthreads();
        part[tid] += v;
        __syncthreads();
    }
    int run = (tid == 0) ? 0 : part[tid - 1];
    for (int i = lo; i < hi; ++i) {
        int t = deg[i];
        off[i] = run;
        run += t;
    }
    if (lo < n && hi == n) off[n] = run;
}

// Column prefix (in place): h2[c][b] <- off[b] + sum_{c'<c} h2[c'][b].
// Converts hist2d into per-chunk write cursors.
__global__ __launch_bounds__(256) void colprefix(int* __restrict__ h2,
                                                 const int* __restrict__ off, int n) {
    int b = blockIdx.x * 256 + threadIdx.x;
    if (b >= n) return;
    int run = off[b];
    for (int c = 0; c < NCHUNK; ++c) {
        long long i = (long long)c * n + b;
        int t = h2[i];
        h2[i] = run;
        run += t;
    }
}

// Pass B: fill both CSRs in one edge read; atomics hit the block's own chunk
// row (uncontended across chunks).
__global__ __launch_bounds__(256) void fill2(const int* __restrict__ src,
                                             const int* __restrict__ dst,
                                             int* __restrict__ h2s,
                                             int* __restrict__ h2v,
                                             int* __restrict__ adj_s,
                                             int* __restrict__ adj_v) {
    int blk = blockIdx.x;
    int chunk = blk >> BLK_PER_CHUNK_SHIFT;
    int lo = blk * EPB, hi = lo + EPB;
    int* rs = h2s + (long long)chunk * N_SITE;
    int* rv = h2v + (long long)chunk * N_VENDOR;
    for (int e = lo + threadIdx.x; e < hi; e += 256) {
        int s = src[e], d = dst[e];
        int ps = atomicAdd(&rs[s], 1);
        adj_s[ps] = d;
        int pv = atomicAdd(&rv[d], 1);
        adj_v[pv] = s;
    }
}

// ---------------------------------------------------------------------------
// Fused layer-1: per-node gather of KA-dim raw neighbor rows + mean-project
// + self-project + biases + relu. One wave (64 lanes) per node.
template<int KA, int KX>
__global__ __launch_bounds__(256) void gc1(const float* __restrict__ feat_src,
                                           const float* __restrict__ feat_self,
                                           const int* __restrict__ off,
                                           const int* __restrict__ adj,
                                           const float* __restrict__ M,
                                           const float* __restrict__ v64,
                                           const float* __restrict__ bl,
                                           const float* __restrict__ R,
                                           const float* __restrict__ rvec,
                                           float* __restrict__ x1, int n) {
    int w = (blockIdx.x * 256 + threadIdx.x) >> 6;
    int lane = threadIdx.x & 63;
    if (w >= n) return;
    int lo = off[w], hi = off[w + 1];
    int deg = hi - lo;
    float s[KA];
    #pragma unroll
    for (int k = 0; k < KA; ++k) s[k] = 0.f;
    for (int j = lo + lane; j < hi; j += 64) {
        const float* fr = feat_src + (long long)adj[j] * KA;
        #pragma unroll
        for (int k = 0; k < KA; ++k) s[k] += fr[k];
    }
    #pragma unroll
    for (int k = 0; k < KA; ++k) {
        #pragma unroll
        for (int m = 32; m >= 1; m >>= 1) s[k] += __shfl_xor(s[k], m, 64);
    }
    float inv = 1.0f / (float)max(deg, 1);
    float acc = bl[lane] + rvec[lane] + (deg > 0 ? v64[lane] : 0.f);
    #pragma unroll
    for (int k = 0; k < KA; ++k) acc = fmaf(s[k] * inv, M[k * 64 + lane], acc);
    const float* xr = feat_self + (long long)w * KX;
    #pragma unroll
    for (int k = 0; k < KX; ++k) acc = fmaf(xr[k], R[k * 64 + lane], acc);
    x1[(long long)w * 64 + lane] = fmaxf(acc, 0.f);
}

// ---------------------------------------------------------------------------
// Y[n,32] = X[n,64] @ W[64,32]  (pre-projection for layer-2 aggregation)
__global__ __launch_bounds__(256) void proj32(const float* __restrict__ X,
                                              const float* __restrict__ W,
                                              float* __restrict__ Y, int n) {
    __shared__ float sW[64 * 32];
    for (int i = threadIdx.x; i < 64 * 32; i += 256) sW[i] = W[i];
    __syncthreads();
    int idx = blockIdx.x * 256 + threadIdx.x;
    if (idx >= n * 32) return;
    int i = idx >> 5, c = idx & 31;
    const float* xr = X + (long long)i * 64;
    float acc = 0.f;
    #pragma unroll
    for (int k = 0; k < 64; ++k) acc = fmaf(xr[k], sW[k * 32 + c], acc);
    Y[idx] = acc;
}

// ---------------------------------------------------------------------------
// Fused layer-2: per-node gather of 32-dim pre-projected rows + mean + bias
// + self(64)@Wr + relu. One wave per node; lanes = 2 edges x 32 cols.
__global__ __launch_bounds__(256) void gc2(const float* __restrict__ y,
                                           const float* __restrict__ Xself,
                                           const int* __restrict__ off,
                                           const int* __restrict__ adj,
                                           const float* __restrict__ Wr,
                                           const float* __restrict__ b,
                                           float* __restrict__ outp, int n) {
    int w = (blockIdx.x * 256 + threadIdx.x) >> 6;
    int lane = threadIdx.x & 63;
    if (w >= n) return;
    int c = lane & 31, g = lane >> 5;
    int lo = off[w], hi = off[w + 1];
    int deg = hi - lo;
    float s = 0.f;
    for (int j = lo + g; j < hi; j += 2)
        s += y[(long long)adj[j] * 32 + c];
    s += __shfl_xor(s, 32, 64);
    float inv = 1.0f / (float)max(deg, 1);
    float acc = s * inv + b[c];
    const float* xr = Xself + (long long)w * 64;
    #pragma unroll
    for (int k = 0; k < 64; ++k) acc = fmaf(xr[k], Wr[k * 32 + c], acc);
    if (g == 0) outp[(long long)w * 32 + c] = fmaxf(acc, 0.f);
}

// ---------------------------------------------------------------------------
extern "C" void kernel_launch(void* const* d_in, const int* in_sizes, int n_in,
                              void* d_out, int out_size, void* d_ws, size_t ws_size,
                              hipStream_t stream) {
    const float* x_site      = (const float*)d_in[0];
    const float* x_vendor    = (const float*)d_in[1];
    const int*   src         = (const int*)d_in[2];
    const int*   dst         = (const int*)d_in[3];
    const float* W_site_in   = (const float*)d_in[4];
    const float* b_site_in   = (const float*)d_in[5];
    const float* W_vendor_in = (const float*)d_in[6];
    const float* b_vendor_in = (const float*)d_in[7];
    const float* Wl1sv = (const float*)d_in[8];
    const float* bl1sv = (const float*)d_in[9];
    const float* Wr1sv = (const float*)d_in[10];
    const float* Wl1vs = (const float*)d_in[11];
    const float* bl1vs = (const float*)d_in[12];
    const float* Wr1vs = (const float*)d_in[13];
    const float* Wl2sv = (const float*)d_in[14];
    const float* bl2sv = (const float*)d_in[15];
    const float* Wr2sv = (const float*)d_in[16];
    const float* Wl2vs = (const float*)d_in[17];
    const float* bl2vs = (const float*)d_in[18];
    const float* Wr2vs = (const float*)d_in[19];

    // Guard: never write past harness scratch (overrun can kill the container).
    if (ws_size < (size_t)WS_WORDS * 4) return;

    int*   wi  = (int*)d_ws;
    float* wf  = (float*)d_ws;
    float* out = (float*)d_out;

    int* deg_v = wi + I_DEG_V;
    int* deg_s = wi + I_DEG_S;
    int* off_v = wi + I_OFF_V;
    int* off_s = wi + I_OFF_S;
    int* adj_v = wi + I_ADJ_V;
    int* adj_s = wi + I_ADJ_S;
    int* h2s   = wi + A_H2S;   // aliases xs1 (dead until gc1)
    int* h2v   = wi + A_H2V;
    float* xs1   = wf + F_XS1;
    float* xv1   = wf + F_XV1;
    float* ys    = wf + F_YS;
    float* yv    = wf + F_YV;
    float* fused = wf + F_FUSED;

    // zero hist tables (ws not re-poisoned between replays; zero every call)
    hipMemsetAsync(h2s, 0, (size_t)H2_WORDS * sizeof(int), stream);

    fuse_weights<<<11, 256, 0, stream>>>(W_site_in, b_site_in, W_vendor_in, b_vendor_in,
                                         Wl1sv, Wr1sv, Wl1vs, Wr1vs, fused);

    // --- CSR build: chunked counting sort, uncontended atomics, no LDS ---
    hist2d<<<NBLK, 256, 0, stream>>>(src, dst, h2s, h2v);
    colsum<<<(N_SITE + 255) / 256, 256, 0, stream>>>(h2s, deg_s, N_SITE);
    colsum<<<(N_VENDOR + 255) / 256, 256, 0, stream>>>(h2v, deg_v, N_VENDOR);
    scank<<<1, 1024, 0, stream>>>(deg_s, off_s, N_SITE);
    scank<<<1, 1024, 0, stream>>>(deg_v, off_v, N_VENDOR);
    colprefix<<<(N_SITE + 255) / 256, 256, 0, stream>>>(h2s, off_s, N_SITE);
    colprefix<<<(N_VENDOR + 255) / 256, 256, 0, stream>>>(h2v, off_v, N_VENDOR);
    fill2<<<NBLK, 256, 0, stream>>>(src, dst, h2s, h2v, adj_s, adj_v);

    // --- layer 1 (fused gather+project+self+relu), raw-feature aggregation ---
    gc1<VENDOR_IN, SITE_IN><<<(N_SITE + 3) / 4, 256, 0, stream>>>(
        x_vendor, x_site, off_s, adj_s,
        fused + F_M1VS, fused + F_V1VS, bl1vs, fused + F_R1VS, fused + F_r1VS,
        xs1, N_SITE);
    gc1<SITE_IN, VENDOR_IN><<<(N_VENDOR + 3) / 4, 256, 0, stream>>>(
        x_site, x_vendor, off_v, adj_v,
        fused + F_M1SV, fused + F_V1SV, bl1sv, fused + F_R1SV, fused + F_r1SV,
        xv1, N_VENDOR);

    // --- layer-2 pre-projections ---
    proj32<<<(N_SITE * 32 + 255) / 256, 256, 0, stream>>>(xs1, Wl2sv, ys, N_SITE);
    proj32<<<(N_VENDOR * 32 + 255) / 256, 256, 0, stream>>>(xv1, Wl2vs, yv, N_VENDOR);

    // --- layer 2 (fused gather+mean+self+relu) straight into d_out ---
    gc2<<<(N_VENDOR + 3) / 4, 256, 0, stream>>>(ys, xv1, off_v, adj_v,
                                                Wr2sv, bl2sv,
                                                out + (long long)N_SITE * OUT, N_VENDOR);
    gc2<<<(N_SITE + 3) / 4, 256, 0, stream>>>(yv, xs1, off_s, adj_s,
                                              Wr2vs, bl2vs, out, N_SITE);

    (void)in_sizes; (void)n_in; (void)out_size;
}

// Round 5
// 680.054 us; speedup vs baseline: 6.0813x; 2.2121x over previous
//
#include <hip/hip_runtime.h>

// Problem constants
constexpr int N_SITE    = 100000;
constexpr int N_VENDOR  = 20000;
constexpr int NE        = 3200000;
constexpr int SITE_IN   = 10;
constexpr int VENDOR_IN = 9;
constexpr int HID       = 64;
constexpr int OUT       = 32;

// Radix-build parameters
constexpr int NBLK    = 1024;            // pass-1 grid (each block = one chunk)
constexpr int EPB     = NE / NBLK;       // 3125 edges per block
constexpr int SHIFT_S = 8;               // 256 sites per bucket
constexpr int NBUK_S  = (N_SITE + 255) / 256;    // 391
constexpr int SHIFT_V = 7;               // 128 vendors per bucket
constexpr int NBUK_V  = (N_VENDOR + 127) / 128;  // 157

// ---------------------------------------------------------------------------
// Workspace layout (4-byte words).
constexpr long long I_OFF_V  = 0;                                // [N_VENDOR+1]
constexpr long long I_OFF_S  = I_OFF_V + N_VENDOR + 1;           // [N_SITE+1]
constexpr long long I_BASE_S = I_OFF_S + N_SITE + 1;             // [NBUK_S+1]
constexpr long long I_BASE_V = I_BASE_S + NBUK_S + 1;            // [NBUK_V+1]
constexpr long long I_TOT    = I_BASE_V + NBUK_V + 1;            // [NBUK_S+NBUK_V] zeroed/call
constexpr long long I_ADJ_V  = I_TOT + NBUK_S + NBUK_V;          // [NE]
constexpr long long I_ADJ_S  = I_ADJ_V + NE;                     // [NE]
constexpr long long INT_END  = I_ADJ_S + NE;
// Build scratch (h2 cursor tables + pairs) aliases the float intermediates:
// floats are only written after the build completes.
constexpr long long A_H2S    = INT_END;                          // [NBLK*NBUK_S]
constexpr long long A_H2V    = A_H2S + (long long)NBLK * NBUK_S; // [NBLK*NBUK_V]
constexpr long long A_PAIRS  = (A_H2V + (long long)NBLK * NBUK_V + 1) & ~1LL; // int2-aligned
constexpr long long BUILD_END = A_PAIRS + 2LL * NE;
constexpr long long F_XS1    = INT_END;                          // [100000*64]
constexpr long long F_XV1    = F_XS1 + (long long)N_SITE * HID;  // [20000*64]
constexpr long long F_YS     = F_XV1 + (long long)N_VENDOR * HID;// [100000*32]
constexpr long long F_YV     = F_YS  + (long long)N_SITE * OUT;  // [20000*32]
constexpr long long F_END    = F_YV  + (long long)N_VENDOR * OUT;
constexpr long long SHARED_END = (BUILD_END > F_END) ? BUILD_END : F_END;
constexpr long long F_FUSED  = SHARED_END;                       // [2688]
constexpr long long WS_WORDS = F_FUSED + 2688;                   // ~72.2 MB

// fused sub-offsets
constexpr int F_M1SV = 0;     // 10x64  W_site_in@Wl1sv
constexpr int F_V1SV = 640;   // 64     b_site_in@Wl1sv
constexpr int F_M1VS = 704;   // 9x64   W_vendor_in@Wl1vs
constexpr int F_V1VS = 1280;  // 64     b_vendor_in@Wl1vs
constexpr int F_R1SV = 1344;  // 9x64   W_vendor_in@Wr1sv  (vendor self term)
constexpr int F_r1SV = 1920;  // 64     b_vendor_in@Wr1sv
constexpr int F_R1VS = 1984;  // 10x64  W_site_in@Wr1vs    (site self term)
constexpr int F_r1VS = 2624;  // 64     b_site_in@Wr1vs

// ---------------------------------------------------------------------------
// Fold input projection + layer-1 weights into tiny fused matrices.
__global__ void fuse_weights(const float* __restrict__ Wsi, const float* __restrict__ bsi,
                             const float* __restrict__ Wvi, const float* __restrict__ bvi,
                             const float* __restrict__ Wl1sv, const float* __restrict__ Wr1sv,
                             const float* __restrict__ Wl1vs, const float* __restrict__ Wr1vs,
                             float* __restrict__ fused) {
    int idx = blockIdx.x * blockDim.x + threadIdx.x;
    if (idx < 640) { int k = idx >> 6, c = idx & 63; float s = 0.f;
        for (int j = 0; j < 64; ++j) s = fmaf(Wsi[k*64+j], Wl1sv[j*64+c], s);
        fused[F_M1SV + idx] = s; return; }
    idx -= 640;
    if (idx < 64) { float s = 0.f;
        for (int j = 0; j < 64; ++j) s = fmaf(bsi[j], Wl1sv[j*64+idx], s);
        fused[F_V1SV + idx] = s; return; }
    idx -= 64;
    if (idx < 576) { int k = idx / 64, c = idx & 63; float s = 0.f;
        for (int j = 0; j < 64; ++j) s = fmaf(Wvi[k*64+j], Wl1vs[j*64+c], s);
        fused[F_M1VS + idx] = s; return; }
    idx -= 576;
    if (idx < 64) { float s = 0.f;
        for (int j = 0; j < 64; ++j) s = fmaf(bvi[j], Wl1vs[j*64+idx], s);
        fused[F_V1VS + idx] = s; return; }
    idx -= 64;
    if (idx < 576) { int k = idx / 64, c = idx & 63; float s = 0.f;
        for (int j = 0; j < 64; ++j) s = fmaf(Wvi[k*64+j], Wr1sv[j*64+c], s);
        fused[F_R1SV + idx] = s; return; }
    idx -= 576;
    if (idx < 64) { float s = 0.f;
        for (int j = 0; j < 64; ++j) s = fmaf(bvi[j], Wr1sv[j*64+idx], s);
        fused[F_r1SV + idx] = s; return; }
    idx -= 64;
    if (idx < 640) { int k = idx >> 6, c = idx & 63; float s = 0.f;
        for (int j = 0; j < 64; ++j) s = fmaf(Wsi[k*64+j], Wr1vs[j*64+c], s);
        fused[F_R1VS + idx] = s; return; }
    idx -= 640;
    if (idx < 64) { float s = 0.f;
        for (int j = 0; j < 64; ++j) s = fmaf(bsi[j], Wr1vs[j*64+idx], s);
        fused[F_r1VS + idx] = s; return; }
}

// ---------------------------------------------------------------------------
// Build K1: per-block LDS bucket histograms for BOTH directions in one edge
// read. Writes private h2 rows (no atomics) + merges bucket totals.
__global__ __launch_bounds__(256) void histbk(const int* __restrict__ src,
                                              const int* __restrict__ dst,
                                              int* __restrict__ h2s,
                                              int* __restrict__ h2v,
                                              int* __restrict__ tot) {
    __shared__ int hs[NBUK_S];
    __shared__ int hv[NBUK_V];
    int blk = blockIdx.x, tid = threadIdx.x;
    for (int i = tid; i < NBUK_S; i += 256) hs[i] = 0;
    for (int i = tid; i < NBUK_V; i += 256) hv[i] = 0;
    __syncthreads();
    int lo = blk * EPB;
    for (int e = lo + tid; e < lo + EPB; e += 256) {
        atomicAdd(&hs[src[e] >> SHIFT_S], 1);
        atomicAdd(&hv[dst[e] >> SHIFT_V], 1);
    }
    __syncthreads();
    for (int i = tid; i < NBUK_S; i += 256) {
        int c = hs[i];
        h2s[(long long)blk * NBUK_S + i] = c;
        if (c) atomicAdd(&tot[i], c);
    }
    for (int i = tid; i < NBUK_V; i += 256) {
        int c = hv[i];
        h2v[(long long)blk * NBUK_V + i] = c;
        if (c) atomicAdd(&tot[NBUK_S + i], c);
    }
}

// Build K2: exclusive scan of bucket totals -> bucket base offsets.
__global__ __launch_bounds__(512) void basescan(const int* __restrict__ tot,
                                                int* __restrict__ base_s,
                                                int* __restrict__ base_v) {
    __shared__ int a[512];
    int tid = threadIdx.x;
    int v = (tid < NBUK_S) ? tot[tid] : 0;
    a[tid] = v; __syncthreads();
    for (int st = 1; st < 512; st <<= 1) {
        int x = (tid >= st) ? a[tid - st] : 0; __syncthreads();
        a[tid] += x; __syncthreads();
    }
    if (tid < NBUK_S) base_s[tid] = a[tid] - v;
    if (tid == 0) base_s[NBUK_S] = NE;
    __syncthreads();
    int w = (tid < NBUK_V) ? tot[NBUK_S + tid] : 0;
    a[tid] = w; __syncthreads();
    for (int st = 1; st < 512; st <<= 1) {
        int x = (tid >= st) ? a[tid - st] : 0; __syncthreads();
        a[tid] += x; __syncthreads();
    }
    if (tid < NBUK_V) base_v[tid] = a[tid] - w;
    if (tid == 0) base_v[NBUK_V] = NE;
}

// Build K3: convert h2 counts into per-(chunk,bucket) write cursors:
// h2[c][b] <- base[b] + sum_{c'<c} cnt[c'][b]. One block per bucket.
__global__ __launch_bounds__(256) void cursorize(int* __restrict__ h2s,
                                                 int* __restrict__ h2v,
                                                 const int* __restrict__ base_s,
                                                 const int* __restrict__ base_v) {
    int b = blockIdx.x, tid = threadIdx.x;
    int* h2; const int* base; int nbuk;
    if (b < NBUK_S) { h2 = h2s; base = base_s; nbuk = NBUK_S; }
    else            { b -= NBUK_S; h2 = h2v; base = base_v; nbuk = NBUK_V; }
    int c[4], loc[4], s = 0;
    #pragma unroll
    for (int i = 0; i < 4; ++i) c[i] = h2[(long long)(tid * 4 + i) * nbuk + b];
    #pragma unroll
    for (int i = 0; i < 4; ++i) { loc[i] = s; s += c[i]; }
    __shared__ int p[256];
    p[tid] = s; __syncthreads();
    for (int st = 1; st < 256; st <<= 1) {
        int x = (tid >= st) ? p[tid - st] : 0; __syncthreads();
        p[tid] += x; __syncthreads();
    }
    int pre = base[b] + (tid ? p[tid - 1] : 0);
    #pragma unroll
    for (int i = 0; i < 4; ++i) h2[(long long)(tid * 4 + i) * nbuk + b] = pre + loc[i];
}

// Build K4: pass-1 scatter of (key,val) pairs into bucket-grouped order.
// Cursors are per-block LDS (no global atomics); each block's writes per
// bucket are contiguous runs -> L2-absorbed.
template<int NBUK, int SHIFT>
__global__ __launch_bounds__(256) void scatter1(const int* __restrict__ key,
                                                const int* __restrict__ val,
                                                const int* __restrict__ h2,
                                                int2* __restrict__ pairs) {
    __shared__ int cur[NBUK];
    int blk = blockIdx.x, tid = threadIdx.x;
    for (int i = tid; i < NBUK; i += 256) cur[i] = h2[(long long)blk * NBUK + i];
    __syncthreads();
    int lo = blk * EPB;
    for (int e = lo + tid; e < lo + EPB; e += 256) {
        int k = key[e];
        int p = atomicAdd(&cur[k >> SHIFT], 1);
        pairs[p] = make_int2(k, val[e]);
    }
}

// Build K5: pass-2 per-bucket counting sort. One block per bucket: LDS degree
// hist + scan -> coalesced off[] write + scatter into the bucket's own
// contiguous (L2-hot, 32-80KB) adj region.
template<int BW, int SHIFT>
__global__ __launch_bounds__(256) void stage2(const int2* __restrict__ pairs,
                                              const int* __restrict__ base,
                                              int* __restrict__ off,
                                              int* __restrict__ adj,
                                              int nnode, int nbuk) {
    int b = blockIdx.x, tid = threadIdx.x;
    int lo_node = b << SHIFT;
    int p0 = base[b], p1 = base[b + 1];
    __shared__ int deg[BW];
    __shared__ int cur[BW];
    __shared__ int sc[256];
    if (tid < BW) deg[tid] = 0;
    __syncthreads();
    for (int e = p0 + tid; e < p1; e += 256)
        atomicAdd(&deg[pairs[e].x - lo_node], 1);
    __syncthreads();
    int d = (tid < BW) ? deg[tid] : 0;
    sc[tid] = d;
    __syncthreads();
    for (int st = 1; st < 256; st <<= 1) {
        int x = (tid >= st) ? sc[tid - st] : 0; __syncthreads();
        sc[tid] += x; __syncthreads();
    }
    int excl = sc[tid] - d;
    if (tid < BW) {
        int node = lo_node + tid;
        if (node < nnode) off[node] = p0 + excl;
        cur[tid] = p0 + excl;
    }
    if (b == nbuk - 1 && tid == 0) off[nnode] = NE;
    __syncthreads();
    for (int e = p0 + tid; e < p1; e += 256) {
        int2 pr = pairs[e];
        int p = atomicAdd(&cur[pr.x - lo_node], 1);
        adj[p] = pr.y;
    }
}

// ---------------------------------------------------------------------------
// Fused layer-1: per-node gather of KA-dim raw neighbor rows + mean-project
// + self-project + biases + relu. One wave (64 lanes) per node.
template<int KA, int KX>
__global__ __launch_bounds__(256) void gc1(const float* __restrict__ feat_src,
                                           const float* __restrict__ feat_self,
                                           const int* __restrict__ off,
                                           const int* __restrict__ adj,
                                           const float* __restrict__ M,
                                           const float* __restrict__ v64,
                                           const float* __restrict__ bl,
                                           const float* __restrict__ R,
                                           const float* __restrict__ rvec,
                                           float* __restrict__ x1, int n) {
    int w = (blockIdx.x * 256 + threadIdx.x) >> 6;
    int lane = threadIdx.x & 63;
    if (w >= n) return;
    int lo = off[w], hi = off[w + 1];
    int deg = hi - lo;
    float s[KA];
    #pragma unroll
    for (int k = 0; k < KA; ++k) s[k] = 0.f;
    for (int j = lo + lane; j < hi; j += 64) {
        const float* fr = feat_src + (long long)adj[j] * KA;
        #pragma unroll
        for (int k = 0; k < KA; ++k) s[k] += fr[k];
    }
    #pragma unroll
    for (int k = 0; k < KA; ++k) {
        #pragma unroll
        for (int m = 32; m >= 1; m >>= 1) s[k] += __shfl_xor(s[k], m, 64);
    }
    float inv = 1.0f / (float)max(deg, 1);
    float acc = bl[lane] + rvec[lane] + (deg > 0 ? v64[lane] : 0.f);
    #pragma unroll
    for (int k = 0; k < KA; ++k) acc = fmaf(s[k] * inv, M[k * 64 + lane], acc);
    const float* xr = feat_self + (long long)w * KX;
    #pragma unroll
    for (int k = 0; k < KX; ++k) acc = fmaf(xr[k], R[k * 64 + lane], acc);
    x1[(long long)w * 64 + lane] = fmaxf(acc, 0.f);
}

// ---------------------------------------------------------------------------
// Y[n,32] = X[n,64] @ W[64,32]  (pre-projection for layer-2 aggregation)
__global__ __launch_bounds__(256) void proj32(const float* __restrict__ X,
                                              const float* __restrict__ W,
                                              float* __restrict__ Y, int n) {
    __shared__ float sW[64 * 32];
    for (int i = threadIdx.x; i < 64 * 32; i += 256) sW[i] = W[i];
    __syncthreads();
    int idx = blockIdx.x * 256 + threadIdx.x;
    if (idx >= n * 32) return;
    int i = idx >> 5, c = idx & 31;
    const float* xr = X + (long long)i * 64;
    float acc = 0.f;
    #pragma unroll
    for (int k = 0; k < 64; ++k) acc = fmaf(xr[k], sW[k * 32 + c], acc);
    Y[idx] = acc;
}

// ---------------------------------------------------------------------------
// Fused layer-2: per-node gather of 32-dim pre-projected rows + mean + bias
// + self(64)@Wr + relu. One wave per node; lanes = 2 edges x 32 cols.
__global__ __launch_bounds__(256) void gc2(const float* __restrict__ y,
                                           const float* __restrict__ Xself,
                                           const int* __restrict__ off,
                                           const int* __restrict__ adj,
                                           const float* __restrict__ Wr,
                                           const float* __restrict__ b,
                                           float* __restrict__ outp, int n) {
    int w = (blockIdx.x * 256 + threadIdx.x) >> 6;
    int lane = threadIdx.x & 63;
    if (w >= n) return;
    int c = lane & 31, g = lane >> 5;
    int lo = off[w], hi = off[w + 1];
    int deg = hi - lo;
    float s = 0.f;
    for (int j = lo + g; j < hi; j += 2)
        s += y[(long long)adj[j] * 32 + c];
    s += __shfl_xor(s, 32, 64);
    float inv = 1.0f / (float)max(deg, 1);
    float acc = s * inv + b[c];
    const float* xr = Xself + (long long)w * 64;
    #pragma unroll
    for (int k = 0; k < 64; ++k) acc = fmaf(xr[k], Wr[k * 32 + c], acc);
    if (g == 0) outp[(long long)w * 32 + c] = fmaxf(acc, 0.f);
}

// ---------------------------------------------------------------------------
extern "C" void kernel_launch(void* const* d_in, const int* in_sizes, int n_in,
                              void* d_out, int out_size, void* d_ws, size_t ws_size,
                              hipStream_t stream) {
    const float* x_site      = (const float*)d_in[0];
    const float* x_vendor    = (const float*)d_in[1];
    const int*   src         = (const int*)d_in[2];
    const int*   dst         = (const int*)d_in[3];
    const float* W_site_in   = (const float*)d_in[4];
    const float* b_site_in   = (const float*)d_in[5];
    const float* W_vendor_in = (const float*)d_in[6];
    const float* b_vendor_in = (const float*)d_in[7];
    const float* Wl1sv = (const float*)d_in[8];
    const float* bl1sv = (const float*)d_in[9];
    const float* Wr1sv = (const float*)d_in[10];
    const float* Wl1vs = (const float*)d_in[11];
    const float* bl1vs = (const float*)d_in[12];
    const float* Wr1vs = (const float*)d_in[13];
    const float* Wl2sv = (const float*)d_in[14];
    const float* bl2sv = (const float*)d_in[15];
    const float* Wr2sv = (const float*)d_in[16];
    const float* Wl2vs = (const float*)d_in[17];
    const float* bl2vs = (const float*)d_in[18];
    const float* Wr2vs = (const float*)d_in[19];

    // Guard: never write past harness scratch (overrun can kill the container).
    if (ws_size < (size_t)WS_WORDS * 4) return;

    int*   wi  = (int*)d_ws;
    float* wf  = (float*)d_ws;
    float* out = (float*)d_out;

    int* off_v  = wi + I_OFF_V;
    int* off_s  = wi + I_OFF_S;
    int* base_s = wi + I_BASE_S;
    int* base_v = wi + I_BASE_V;
    int* tot    = wi + I_TOT;
    int* adj_v  = wi + I_ADJ_V;
    int* adj_s  = wi + I_ADJ_S;
    int* h2s    = wi + A_H2S;     // aliases float region (floats written post-build)
    int* h2v    = wi + A_H2V;
    int2* pairs = (int2*)(wi + A_PAIRS);
    float* xs1   = wf + F_XS1;
    float* xv1   = wf + F_XV1;
    float* ys    = wf + F_YS;
    float* yv    = wf + F_YV;
    float* fused = wf + F_FUSED;

    // zero bucket totals (ws not re-poisoned between replays; zero every call)
    hipMemsetAsync(tot, 0, (size_t)(NBUK_S + NBUK_V) * sizeof(int), stream);

    fuse_weights<<<11, 256, 0, stream>>>(W_site_in, b_site_in, W_vendor_in, b_vendor_in,
                                         Wl1sv, Wr1sv, Wl1vs, Wr1vs, fused);

    // --- CSR build: two-level radix, all scatters L2-absorbed ---
    histbk<<<NBLK, 256, 0, stream>>>(src, dst, h2s, h2v, tot);
    basescan<<<1, 512, 0, stream>>>(tot, base_s, base_v);
    cursorize<<<NBUK_S + NBUK_V, 256, 0, stream>>>(h2s, h2v, base_s, base_v);
    // site direction (adj_s: vendors grouped by site)
    scatter1<NBUK_S, SHIFT_S><<<NBLK, 256, 0, stream>>>(src, dst, h2s, pairs);
    stage2<256, SHIFT_S><<<NBUK_S, 256, 0, stream>>>(pairs, base_s, off_s, adj_s,
                                                     N_SITE, NBUK_S);
    // vendor direction (adj_v: sites grouped by vendor) — reuses pairs buffer
    scatter1<NBUK_V, SHIFT_V><<<NBLK, 256, 0, stream>>>(dst, src, h2v, pairs);
    stage2<128, SHIFT_V><<<NBUK_V, 256, 0, stream>>>(pairs, base_v, off_v, adj_v,
                                                     N_VENDOR, NBUK_V);

    // --- layer 1 (fused gather+project+self+relu), raw-feature aggregation ---
    gc1<VENDOR_IN, SITE_IN><<<(N_SITE + 3) / 4, 256, 0, stream>>>(
        x_vendor, x_site, off_s, adj_s,
        fused + F_M1VS, fused + F_V1VS, bl1vs, fused + F_R1VS, fused + F_r1VS,
        xs1, N_SITE);
    gc1<SITE_IN, VENDOR_IN><<<(N_VENDOR + 3) / 4, 256, 0, stream>>>(
        x_site, x_vendor, off_v, adj_v,
        fused + F_M1SV, fused + F_V1SV, bl1sv, fused + F_R1SV, fused + F_r1SV,
        xv1, N_VENDOR);

    // --- layer-2 pre-projections ---
    proj32<<<(N_SITE * 32 + 255) / 256, 256, 0, stream>>>(xs1, Wl2sv, ys, N_SITE);
    proj32<<<(N_VENDOR * 32 + 255) / 256, 256, 0, stream>>>(xv1, Wl2vs, yv, N_VENDOR);

    // --- layer 2 (fused gather+mean+self+relu) straight into d_out ---
    gc2<<<(N_VENDOR + 3) / 4, 256, 0, stream>>>(ys, xv1, off_v, adj_v,
                                                Wr2sv, bl2sv,
                                                out + (long long)N_SITE * OUT, N_VENDOR);
    gc2<<<(N_SITE + 3) / 4, 256, 0, stream>>>(yv, xs1, off_s, adj_s,
                                              Wr2vs, bl2vs, out, N_SITE);

    (void)in_sizes; (void)n_in; (void)out_size;
}

// Round 6
// 495.667 us; speedup vs baseline: 8.3436x; 1.3720x over previous
//
#include <hip/hip_runtime.h>

// Problem constants
constexpr int N_SITE    = 100000;
constexpr int N_VENDOR  = 20000;
constexpr int NE        = 3200000;
constexpr int SITE_IN   = 10;
constexpr int VENDOR_IN = 9;
constexpr int HID       = 64;
constexpr int OUT       = 32;

// Radix-build parameters
constexpr int NBLK    = 1024;            // pass-1 grid (each block = one chunk)
constexpr int EPB     = NE / NBLK;       // 3125 edges per block
constexpr int SHIFT_S = 8;               // 256 sites per bucket
constexpr int NBUK_S  = (N_SITE + 255) / 256;    // 391
constexpr int SHIFT_V = 7;               // 128 vendors per bucket
constexpr int NBUK_V  = (N_VENDOR + 127) / 128;  // 157

// Merged-launch block ranges
constexpr int SB1  = (N_SITE + 3) / 4;           // 25000 (gc1/gc2 site blocks)
constexpr int VB1  = (N_VENDOR + 3) / 4;         // 5000
constexpr int PD_S = (N_SITE + 63) / 64;         // 1563 (projdual site blocks)
constexpr int PD_V = (N_VENDOR + 63) / 64;       // 313

// ---------------------------------------------------------------------------
// Workspace layout (4-byte words).
constexpr long long I_OFF_V  = 0;                                // [N_VENDOR+1]
constexpr long long I_OFF_S  = I_OFF_V + N_VENDOR + 1;           // [N_SITE+1]
constexpr long long I_BASE_S = I_OFF_S + N_SITE + 1;             // [NBUK_S+1]
constexpr long long I_BASE_V = I_BASE_S + NBUK_S + 1;            // [NBUK_V+1]
constexpr long long I_TOT    = I_BASE_V + NBUK_V + 1;            // [NBUK_S+NBUK_V] zeroed/call
constexpr long long I_ADJ_V  = I_TOT + NBUK_S + NBUK_V;          // [NE]
constexpr long long I_ADJ_S  = I_ADJ_V + NE;                     // [NE]
constexpr long long INT_END  = I_ADJ_S + NE;
// Build scratch (h2 cursor tables + pairs) aliases the float intermediates:
// floats are only written after the build completes.
constexpr long long A_H2S    = INT_END;                          // [NBLK*NBUK_S]
constexpr long long A_H2V    = A_H2S + (long long)NBLK * NBUK_S; // [NBLK*NBUK_V]
constexpr long long A_PAIRS  = (A_H2V + (long long)NBLK * NBUK_V + 1) & ~1LL; // int2-aligned
constexpr long long BUILD_END = A_PAIRS + 2LL * NE;
constexpr long long F_XS1    = INT_END;                          // [100000*64]
constexpr long long F_XV1    = F_XS1 + (long long)N_SITE * HID;  // [20000*64]
constexpr long long F_YS     = F_XV1 + (long long)N_VENDOR * HID;// [100000*32]
constexpr long long F_YV     = F_YS  + (long long)N_SITE * OUT;  // [20000*32]
constexpr long long F_END    = F_YV  + (long long)N_VENDOR * OUT;
// Padded features ALIAS the ys/yv region: written by padfeat (early), read by
// gc1 only; projdual overwrites ys/yv strictly after gc1 completes.
constexpr long long F_PAD_S  = F_YS;                             // [100000*12]
constexpr long long F_PAD_V  = F_PAD_S + (long long)N_SITE * 12; // [20000*12]
static_assert(F_PAD_V + (long long)N_VENDOR * 12 <= F_END, "pads fit in ys/yv");
constexpr long long SHARED_END = (BUILD_END > F_END) ? BUILD_END : F_END;
constexpr long long F_FUSED  = SHARED_END;                       // [3328]
constexpr long long WS_WORDS = F_FUSED + 3328;                   // ~72.2 MB

// fused sub-offsets (layer-1 matrices padded to 12 rows; pad rows are ZERO)
constexpr int F_M1SV = 0;      // 12x64  W_site_in@Wl1sv   (rows 10,11 = 0)
constexpr int F_M1VS = 768;    // 12x64  W_vendor_in@Wl1vs (rows 9..11 = 0)
constexpr int F_R1SV = 1536;   // 12x64  W_vendor_in@Wr1sv
constexpr int F_R1VS = 2304;   // 12x64  W_site_in@Wr1vs
constexpr int F_V1SV = 3072;   // 64     b_site_in@Wl1sv
constexpr int F_V1VS = 3136;   // 64     b_vendor_in@Wl1vs
constexpr int F_r1SV = 3200;   // 64     b_vendor_in@Wr1sv
constexpr int F_r1VS = 3264;   // 64     b_site_in@Wr1vs

// ---------------------------------------------------------------------------
// Fold input projection + layer-1 weights into padded fused matrices.
__global__ __launch_bounds__(256) void fuse_weights(
        const float* __restrict__ Wsi, const float* __restrict__ bsi,
        const float* __restrict__ Wvi, const float* __restrict__ bvi,
        const float* __restrict__ Wl1sv, const float* __restrict__ Wr1sv,
        const float* __restrict__ Wl1vs, const float* __restrict__ Wr1vs,
        float* __restrict__ fused) {
    int idx = blockIdx.x * 256 + threadIdx.x;
    if (idx < 3072) {                       // matrices, m = 0..3
        int m = idx / 768, rem = idx % 768, r = rem >> 6, c = rem & 63;
        int K = (m == 0 || m == 3) ? SITE_IN : VENDOR_IN;
        const float* A = (m == 0 || m == 3) ? Wsi : Wvi;
        const float* B = (m == 0) ? Wl1sv : (m == 1) ? Wl1vs : (m == 2) ? Wr1sv : Wr1vs;
        float s = 0.f;
        if (r < K)
            for (int j = 0; j < 64; ++j) s = fmaf(A[r * 64 + j], B[j * 64 + c], s);
        fused[idx] = s;
    } else if (idx < 3328) {                // bias vectors
        int m = (idx - 3072) >> 6, c = idx & 63;
        const float* a = (m == 0 || m == 3) ? bsi : bvi;
        const float* B = (m == 0) ? Wl1sv : (m == 1) ? Wl1vs : (m == 2) ? Wr1sv : Wr1vs;
        float s = 0.f;
        for (int j = 0; j < 64; ++j) s = fmaf(a[j], B[j * 64 + c], s);
        fused[idx] = s;
    }
}

// ---------------------------------------------------------------------------
// Pad raw features to 12 floats/row (16B-aligned float4 gathers in gc1).
__global__ __launch_bounds__(256) void padfeat(const float* __restrict__ x_site,
                                               const float* __restrict__ x_vendor,
                                               float* __restrict__ xsp,
                                               float* __restrict__ xvp) {
    int t = blockIdx.x * 256 + threadIdx.x;
    if (t < N_SITE * 12) {
        int i = t / 12, k = t % 12;
        xsp[t] = (k < SITE_IN) ? x_site[i * SITE_IN + k] : 0.f;
    } else {
        t -= N_SITE * 12;
        if (t < N_VENDOR * 12) {
            int i = t / 12, k = t % 12;
            xvp[t] = (k < VENDOR_IN) ? x_vendor[i * VENDOR_IN + k] : 0.f;
        }
    }
}

// ---------------------------------------------------------------------------
// Build K1: per-block LDS bucket histograms for BOTH directions in one edge
// read. Writes private h2 rows (no atomics) + merges bucket totals.
__global__ __launch_bounds__(256) void histbk(const int* __restrict__ src,
                                              const int* __restrict__ dst,
                                              int* __restrict__ h2s,
                                              int* __restrict__ h2v,
                                              int* __restrict__ tot) {
    __shared__ int hs[NBUK_S];
    __shared__ int hv[NBUK_V];
    int blk = blockIdx.x, tid = threadIdx.x;
    for (int i = tid; i < NBUK_S; i += 256) hs[i] = 0;
    for (int i = tid; i < NBUK_V; i += 256) hv[i] = 0;
    __syncthreads();
    int lo = blk * EPB;
    for (int e = lo + tid; e < lo + EPB; e += 256) {
        atomicAdd(&hs[src[e] >> SHIFT_S], 1);
        atomicAdd(&hv[dst[e] >> SHIFT_V], 1);
    }
    __syncthreads();
    for (int i = tid; i < NBUK_S; i += 256) {
        int c = hs[i];
        h2s[(long long)blk * NBUK_S + i] = c;
        if (c) atomicAdd(&tot[i], c);
    }
    for (int i = tid; i < NBUK_V; i += 256) {
        int c = hv[i];
        h2v[(long long)blk * NBUK_V + i] = c;
        if (c) atomicAdd(&tot[NBUK_S + i], c);
    }
}

// Build K2: exclusive scan of bucket totals -> bucket base offsets.
__global__ __launch_bounds__(512) void basescan(const int* __restrict__ tot,
                                                int* __restrict__ base_s,
                                                int* __restrict__ base_v) {
    __shared__ int a[512];
    int tid = threadIdx.x;
    int v = (tid < NBUK_S) ? tot[tid] : 0;
    a[tid] = v; __syncthreads();
    for (int st = 1; st < 512; st <<= 1) {
        int x = (tid >= st) ? a[tid - st] : 0; __syncthreads();
        a[tid] += x; __syncthreads();
    }
    if (tid < NBUK_S) base_s[tid] = a[tid] - v;
    if (tid == 0) base_s[NBUK_S] = NE;
    __syncthreads();
    int w = (tid < NBUK_V) ? tot[NBUK_S + tid] : 0;
    a[tid] = w; __syncthreads();
    for (int st = 1; st < 512; st <<= 1) {
        int x = (tid >= st) ? a[tid - st] : 0; __syncthreads();
        a[tid] += x; __syncthreads();
    }
    if (tid < NBUK_V) base_v[tid] = a[tid] - w;
    if (tid == 0) base_v[NBUK_V] = NE;
}

// Build K3: convert h2 counts into per-(chunk,bucket) write cursors.
__global__ __launch_bounds__(256) void cursorize(int* __restrict__ h2s,
                                                 int* __restrict__ h2v,
                                                 const int* __restrict__ base_s,
                                                 const int* __restrict__ base_v) {
    int b = blockIdx.x, tid = threadIdx.x;
    int* h2; const int* base; int nbuk;
    if (b < NBUK_S) { h2 = h2s; base = base_s; nbuk = NBUK_S; }
    else            { b -= NBUK_S; h2 = h2v; base = base_v; nbuk = NBUK_V; }
    int c[4], loc[4], s = 0;
    #pragma unroll
    for (int i = 0; i < 4; ++i) c[i] = h2[(long long)(tid * 4 + i) * nbuk + b];
    #pragma unroll
    for (int i = 0; i < 4; ++i) { loc[i] = s; s += c[i]; }
    __shared__ int p[256];
    p[tid] = s; __syncthreads();
    for (int st = 1; st < 256; st <<= 1) {
        int x = (tid >= st) ? p[tid - st] : 0; __syncthreads();
        p[tid] += x; __syncthreads();
    }
    int pre = base[b] + (tid ? p[tid - 1] : 0);
    #pragma unroll
    for (int i = 0; i < 4; ++i) h2[(long long)(tid * 4 + i) * nbuk + b] = pre + loc[i];
}

// Build K4: pass-1 scatter of (key,val) pairs into bucket-grouped order.
template<int NBUK, int SHIFT>
__global__ __launch_bounds__(256) void scatter1(const int* __restrict__ key,
                                                const int* __restrict__ val,
                                                const int* __restrict__ h2,
                                                int2* __restrict__ pairs) {
    __shared__ int cur[NBUK];
    int blk = blockIdx.x, tid = threadIdx.x;
    for (int i = tid; i < NBUK; i += 256) cur[i] = h2[(long long)blk * NBUK + i];
    __syncthreads();
    int lo = blk * EPB;
    for (int e = lo + tid; e < lo + EPB; e += 256) {
        int k = key[e];
        int p = atomicAdd(&cur[k >> SHIFT], 1);
        pairs[p] = make_int2(k, val[e]);
    }
}

// Build K5: pass-2 per-bucket counting sort into the bucket's contiguous
// (L2-hot) adj region; coalesced off[] write.
template<int BW, int SHIFT>
__global__ __launch_bounds__(256) void stage2(const int2* __restrict__ pairs,
                                              const int* __restrict__ base,
                                              int* __restrict__ off,
                                              int* __restrict__ adj,
                                              int nnode, int nbuk) {
    int b = blockIdx.x, tid = threadIdx.x;
    int lo_node = b << SHIFT;
    int p0 = base[b], p1 = base[b + 1];
    __shared__ int deg[BW];
    __shared__ int cur[BW];
    __shared__ int sc[256];
    if (tid < BW) deg[tid] = 0;
    __syncthreads();
    for (int e = p0 + tid; e < p1; e += 256)
        atomicAdd(&deg[pairs[e].x - lo_node], 1);
    __syncthreads();
    int d = (tid < BW) ? deg[tid] : 0;
    sc[tid] = d;
    __syncthreads();
    for (int st = 1; st < 256; st <<= 1) {
        int x = (tid >= st) ? sc[tid - st] : 0; __syncthreads();
        sc[tid] += x; __syncthreads();
    }
    int excl = sc[tid] - d;
    if (tid < BW) {
        int node = lo_node + tid;
        if (node < nnode) off[node] = p0 + excl;
        cur[tid] = p0 + excl;
    }
    if (b == nbuk - 1 && tid == 0) off[nnode] = NE;
    __syncthreads();
    for (int e = p0 + tid; e < p1; e += 256) {
        int2 pr = pairs[e];
        int p = atomicAdd(&cur[pr.x - lo_node], 1);
        adj[p] = pr.y;
    }
}

// ---------------------------------------------------------------------------
// Merged fused layer-1 for both directions: per-node gather of padded 12-dim
// neighbor rows (3x float4) + mean-project + self-project + biases + relu.
// One wave per node. Blocks [0,SB1) = site outputs, [SB1,SB1+VB1) = vendor.
__global__ __launch_bounds__(256) void gc1all(
        const float* __restrict__ xsp, const float* __restrict__ xvp,
        const int* __restrict__ off_s, const int* __restrict__ adj_s,
        const int* __restrict__ off_v, const int* __restrict__ adj_v,
        const float* __restrict__ fused,
        const float* __restrict__ bl1vs, const float* __restrict__ bl1sv,
        float* __restrict__ xs1, float* __restrict__ xv1) {
    int b = blockIdx.x;
    const float *fp, *fs, *M, *V, *BL, *R, *RV;
    const int *off, *adj;
    float* xout; int w, n;
    if (b < SB1) {       // site node: aggregate vendor feats, self = site feats
        w = b * 4 + (threadIdx.x >> 6); n = N_SITE;
        fp = xvp; fs = xsp; off = off_s; adj = adj_s;
        M = fused + F_M1VS; V = fused + F_V1VS; BL = bl1vs;
        R = fused + F_R1VS; RV = fused + F_r1VS;
        xout = xs1;
    } else {             // vendor node
        w = (b - SB1) * 4 + (threadIdx.x >> 6); n = N_VENDOR;
        fp = xsp; fs = xvp; off = off_v; adj = adj_v;
        M = fused + F_M1SV; V = fused + F_V1SV; BL = bl1sv;
        R = fused + F_R1SV; RV = fused + F_r1SV;
        xout = xv1;
    }
    int lane = threadIdx.x & 63;
    if (w >= n) return;
    int lo = off[w], hi = off[w + 1], deg = hi - lo;
    float4 a0 = {0.f, 0.f, 0.f, 0.f}, a1 = a0, a2 = a0;
    for (int j = lo + lane; j < hi; j += 64) {
        const float4* fr = (const float4*)(fp + (long long)adj[j] * 12);
        float4 f0 = fr[0], f1 = fr[1], f2 = fr[2];
        a0.x += f0.x; a0.y += f0.y; a0.z += f0.z; a0.w += f0.w;
        a1.x += f1.x; a1.y += f1.y; a1.z += f1.z; a1.w += f1.w;
        a2.x += f2.x; a2.y += f2.y; a2.z += f2.z; a2.w += f2.w;
    }
    float s[12] = {a0.x, a0.y, a0.z, a0.w, a1.x, a1.y, a1.z, a1.w,
                   a2.x, a2.y, a2.z, a2.w};
    #pragma unroll
    for (int k = 0; k < 12; ++k) {
        #pragma unroll
        for (int m = 32; m >= 1; m >>= 1) s[k] += __shfl_xor(s[k], m, 64);
    }
    float inv = 1.0f / (float)max(deg, 1);
    float acc = BL[lane] + RV[lane] + (deg > 0 ? V[lane] : 0.f);
    #pragma unroll
    for (int k = 0; k < 12; ++k) acc = fmaf(s[k] * inv, M[k * 64 + lane], acc);
    const float4* xr4 = (const float4*)(fs + (long long)w * 12);
    float4 x0 = xr4[0], x1 = xr4[1], x2 = xr4[2];
    acc = fmaf(x0.x, R[0 * 64 + lane], acc);
    acc = fmaf(x0.y, R[1 * 64 + lane], acc);
    acc = fmaf(x0.z, R[2 * 64 + lane], acc);
    acc = fmaf(x0.w, R[3 * 64 + lane], acc);
    acc = fmaf(x1.x, R[4 * 64 + lane], acc);
    acc = fmaf(x1.y, R[5 * 64 + lane], acc);
    acc = fmaf(x1.z, R[6 * 64 + lane], acc);
    acc = fmaf(x1.w, R[7 * 64 + lane], acc);
    acc = fmaf(x2.x, R[8 * 64 + lane], acc);
    acc = fmaf(x2.y, R[9 * 64 + lane], acc);
    acc = fmaf(x2.z, R[10 * 64 + lane], acc);
    acc = fmaf(x2.w, R[11 * 64 + lane], acc);
    xout[(long long)w * 64 + lane] = fmaxf(acc, 0.f);
}

// ---------------------------------------------------------------------------
// Merged dual projection (register-tiled mini-GEMM):
//   [y | z] = X1[n,64] @ [Wl2 | Wr2]   (64 outputs per node)
// y (cols 0..31) -> ys/yv scratch (gathered by the other side's gc2);
// z (cols 32..63) -> written DIRECTLY into d_out (self term; gc2 RMWs it).
// Block = 64 nodes; thread = 4 nodes x 4 cols register tile.
__global__ __launch_bounds__(256) void projdual(
        const float* __restrict__ xs1, const float* __restrict__ xv1,
        const float* __restrict__ Wl2sv, const float* __restrict__ Wr2vs,
        const float* __restrict__ Wl2vs, const float* __restrict__ Wr2sv,
        float* __restrict__ ys, float* __restrict__ yv,
        float* __restrict__ out) {
    __shared__ float sW[64 * 64];
    __shared__ float sX[64 * 65];   // +1 pad: conflict-free 4-node column reads
    int b = blockIdx.x, tid = threadIdx.x;
    const float *X, *Wl, *Wr; float *Y, *Z; int base, n;
    if (b < PD_S) {
        base = b * 64; n = N_SITE; X = xs1;
        Wl = Wl2sv; Wr = Wr2vs; Y = ys; Z = out;
    } else {
        base = (b - PD_S) * 64; n = N_VENDOR; X = xv1;
        Wl = Wl2vs; Wr = Wr2sv; Y = yv; Z = out + (long long)N_SITE * OUT;
    }
    for (int i = tid; i < 4096; i += 256) {
        int k = i >> 6, c = i & 63;
        sW[i] = (c < 32) ? Wl[k * 32 + c] : Wr[k * 32 + (c - 32)];
    }
    for (int i = tid; i < 4096; i += 256) {
        int r = i >> 6, c = i & 63;
        int node = base + r;
        sX[r * 65 + c] = (node < n) ? X[(long long)node * 64 + c] : 0.f;
    }
    __syncthreads();
    int ng = tid >> 4, cg = tid & 15;     // 4-node group, 4-col group
    float acc[4][4] = {};
    for (int k = 0; k < 64; ++k) {
        float4 w4 = *(const float4*)(sW + k * 64 + cg * 4);
        #pragma unroll
        for (int i = 0; i < 4; ++i) {
            float xv = sX[(ng * 4 + i) * 65 + k];
            acc[i][0] = fmaf(xv, w4.x, acc[i][0]);
            acc[i][1] = fmaf(xv, w4.y, acc[i][1]);
            acc[i][2] = fmaf(xv, w4.z, acc[i][2]);
            acc[i][3] = fmaf(xv, w4.w, acc[i][3]);
        }
    }
    #pragma unroll
    for (int i = 0; i < 4; ++i) {
        int node = base + ng * 4 + i;
        if (node >= n) continue;
        float4 v = make_float4(acc[i][0], acc[i][1], acc[i][2], acc[i][3]);
        if (cg < 8)  *(float4*)(Y + (long long)node * 32 + cg * 4) = v;
        else         *(float4*)(Z + (long long)node * 32 + (cg - 8) * 4) = v;
    }
}

// ---------------------------------------------------------------------------
// Merged layer-2 combine for both directions: out = relu(gather_mean + b + z)
// where z was pre-written into d_out by projdual. One wave per node,
// lanes = 2 edges x 32 cols; gather unrolled x4 for MLP.
__global__ __launch_bounds__(256) void gc2all(
        const float* __restrict__ ys, const float* __restrict__ yv,
        const int* __restrict__ off_s, const int* __restrict__ adj_s,
        const int* __restrict__ off_v, const int* __restrict__ adj_v,
        const float* __restrict__ bl2vs, const float* __restrict__ bl2sv,
        float* __restrict__ out) {
    int b = blockIdx.x;
    const float *y, *bias; const int *off, *adj; float* o; int w, n;
    if (b < SB1) {       // site outputs gather vendor pre-projections
        w = b * 4 + (threadIdx.x >> 6); n = N_SITE;
        y = yv; off = off_s; adj = adj_s; bias = bl2vs; o = out;
    } else {
        w = (b - SB1) * 4 + (threadIdx.x >> 6); n = N_VENDOR;
        y = ys; off = off_v; adj = adj_v; bias = bl2sv;
        o = out + (long long)N_SITE * OUT;
    }
    if (w >= n) return;
    int lane = threadIdx.x & 63, c = lane & 31, g = lane >> 5;
    int lo = off[w], hi = off[w + 1], deg = hi - lo;
    int m = (deg > g) ? ((deg - g + 1) >> 1) : 0;   // edges for this lane-group
    const int* ap = adj + lo + g;
    float s = 0.f;
    int t = 0;
    for (; t + 4 <= m; t += 4) {
        int a0 = ap[2 * t], a1 = ap[2 * t + 2], a2 = ap[2 * t + 4], a3 = ap[2 * t + 6];
        s += y[(long long)a0 * 32 + c];
        s += y[(long long)a1 * 32 + c];
        s += y[(long long)a2 * 32 + c];
        s += y[(long long)a3 * 32 + c];
    }
    for (; t < m; ++t) s += y[(long long)ap[2 * t] * 32 + c];
    s += __shfl_xor(s, 32, 64);
    if (g == 0) {
        float inv = 1.0f / (float)max(deg, 1);
        long long oi = (long long)w * 32 + c;
        o[oi] = fmaxf(fmaf(s, inv, bias[c] + o[oi]), 0.f);
    }
}

// ---------------------------------------------------------------------------
extern "C" void kernel_launch(void* const* d_in, const int* in_sizes, int n_in,
                              void* d_out, int out_size, void* d_ws, size_t ws_size,
                              hipStream_t stream) {
    const float* x_site      = (const float*)d_in[0];
    const float* x_vendor    = (const float*)d_in[1];
    const int*   src         = (const int*)d_in[2];
    const int*   dst         = (const int*)d_in[3];
    const float* W_site_in   = (const float*)d_in[4];
    const float* b_site_in   = (const float*)d_in[5];
    const float* W_vendor_in = (const float*)d_in[6];
    const float* b_vendor_in = (const float*)d_in[7];
    const float* Wl1sv = (const float*)d_in[8];
    const float* bl1sv = (const float*)d_in[9];
    const float* Wr1sv = (const float*)d_in[10];
    const float* Wl1vs = (const float*)d_in[11];
    const float* bl1vs = (const float*)d_in[12];
    const float* Wr1vs = (const float*)d_in[13];
    const float* Wl2sv = (const float*)d_in[14];
    const float* bl2sv = (const float*)d_in[15];
    const float* Wr2sv = (const float*)d_in[16];
    const float* Wl2vs = (const float*)d_in[17];
    const float* bl2vs = (const float*)d_in[18];
    const float* Wr2vs = (const float*)d_in[19];

    // Guard: never write past harness scratch (overrun can kill the container).
    if (ws_size < (size_t)WS_WORDS * 4) return;

    int*   wi  = (int*)d_ws;
    float* wf  = (float*)d_ws;
    float* out = (float*)d_out;

    int* off_v  = wi + I_OFF_V;
    int* off_s  = wi + I_OFF_S;
    int* base_s = wi + I_BASE_S;
    int* base_v = wi + I_BASE_V;
    int* tot    = wi + I_TOT;
    int* adj_v  = wi + I_ADJ_V;
    int* adj_s  = wi + I_ADJ_S;
    int* h2s    = wi + A_H2S;     // aliases float region (floats written post-build)
    int* h2v    = wi + A_H2V;
    int2* pairs = (int2*)(wi + A_PAIRS);
    float* xs1   = wf + F_XS1;
    float* xv1   = wf + F_XV1;
    float* ys    = wf + F_YS;
    float* yv    = wf + F_YV;
    float* xsp   = wf + F_PAD_S;  // aliases ys/yv (dead until projdual)
    float* xvp   = wf + F_PAD_V;
    float* fused = wf + F_FUSED;

    // zero bucket totals (ws not re-poisoned between replays; zero every call)
    hipMemsetAsync(tot, 0, (size_t)(NBUK_S + NBUK_V) * sizeof(int), stream);

    fuse_weights<<<13, 256, 0, stream>>>(W_site_in, b_site_in, W_vendor_in, b_vendor_in,
                                         Wl1sv, Wr1sv, Wl1vs, Wr1vs, fused);
    padfeat<<<(12 * (N_SITE + N_VENDOR) + 255) / 256, 256, 0, stream>>>(
        x_site, x_vendor, xsp, xvp);

    // --- CSR build: two-level radix, all scatters L2-absorbed ---
    histbk<<<NBLK, 256, 0, stream>>>(src, dst, h2s, h2v, tot);
    basescan<<<1, 512, 0, stream>>>(tot, base_s, base_v);
    cursorize<<<NBUK_S + NBUK_V, 256, 0, stream>>>(h2s, h2v, base_s, base_v);
    scatter1<NBUK_S, SHIFT_S><<<NBLK, 256, 0, stream>>>(src, dst, h2s, pairs);
    stage2<256, SHIFT_S><<<NBUK_S, 256, 0, stream>>>(pairs, base_s, off_s, adj_s,
                                                     N_SITE, NBUK_S);
    scatter1<NBUK_V, SHIFT_V><<<NBLK, 256, 0, stream>>>(dst, src, h2v, pairs);
    stage2<128, SHIFT_V><<<NBUK_V, 256, 0, stream>>>(pairs, base_v, off_v, adj_v,
                                                     N_VENDOR, NBUK_V);

    // --- layer 1: merged fused gather+project+self+relu (both directions) ---
    gc1all<<<SB1 + VB1, 256, 0, stream>>>(xsp, xvp, off_s, adj_s, off_v, adj_v,
                                          fused, bl1vs, bl1sv, xs1, xv1);

    // --- layer 2 pre-projections + self terms (z straight into d_out) ---
    projdual<<<PD_S + PD_V, 256, 0, stream>>>(xs1, xv1, Wl2sv, Wr2vs, Wl2vs, Wr2sv,
                                              ys, yv, out);

    // --- layer 2: merged gather+mean+bias+self+relu ---
    gc2all<<<SB1 + VB1, 256, 0, stream>>>(ys, yv, off_s, adj_s, off_v, adj_v,
                                          bl2vs, bl2sv, out);

    (void)in_sizes; (void)n_in; (void)out_size;
}

// Round 7
// 448.257 us; speedup vs baseline: 9.2260x; 1.1058x over previous
//
#include <hip/hip_runtime.h>

// Problem constants
constexpr int N_SITE    = 100000;
constexpr int N_VENDOR  = 20000;
constexpr int NE        = 3200000;
constexpr int SITE_IN   = 10;
constexpr int VENDOR_IN = 9;
constexpr int HID       = 64;
constexpr int OUT       = 32;

// Radix-build parameters
constexpr int NBLK    = 1024;            // pass-1 grid (each block = one chunk)
constexpr int EPB     = NE / NBLK;       // 3125 edges per block
constexpr int SHIFT_S = 8;               // 256 sites per bucket
constexpr int NBUK_S  = (N_SITE + 255) / 256;    // 391
constexpr int SHIFT_V = 7;               // 128 vendors per bucket
constexpr int NBUK_V  = (N_VENDOR + 127) / 128;  // 157

// Merged-launch block ranges
constexpr int SB1  = (N_SITE + 3) / 4;           // 25000 (gc1/gc2 site blocks)
constexpr int VB1  = (N_VENDOR + 3) / 4;         // 5000
constexpr int PD_S = (N_SITE + 63) / 64;         // 1563 (projdual site blocks)
constexpr int PD_V = (N_VENDOR + 63) / 64;       // 313

// ---------------------------------------------------------------------------
// Workspace layout (4-byte words).
constexpr long long I_OFF_V  = 0;                                // [N_VENDOR+1]
constexpr long long I_OFF_S  = I_OFF_V + N_VENDOR + 1;           // [N_SITE+1]
constexpr long long I_BASE_S = I_OFF_S + N_SITE + 1;             // [NBUK_S+1]
constexpr long long I_BASE_V = I_BASE_S + NBUK_S + 1;            // [NBUK_V+1]
constexpr long long I_TOT    = I_BASE_V + NBUK_V + 1;            // [NBUK_S+NBUK_V] zeroed/call
constexpr long long I_ADJ_V  = I_TOT + NBUK_S + NBUK_V;          // [NE]
constexpr long long I_ADJ_S  = I_ADJ_V + NE;                     // [NE]
constexpr long long INT_END  = I_ADJ_S + NE;
// Build scratch (h2 cursor tables + pairs) aliases the float intermediates:
// floats are only written after the build completes.
constexpr long long A_H2S    = INT_END;                          // [NBLK*NBUK_S]
constexpr long long A_H2V    = A_H2S + (long long)NBLK * NBUK_S; // [NBLK*NBUK_V]
constexpr long long A_PAIRS  = (A_H2V + (long long)NBLK * NBUK_V + 1) & ~1LL; // int2-aligned
constexpr long long BUILD_END = A_PAIRS + 2LL * NE;              // ~INT_END+6.96M words
constexpr long long F_XS1    = INT_END;                          // [100000*64] fp32
constexpr long long F_XV1    = F_XS1 + (long long)N_SITE * HID;  // [20000*64]  fp32
// 3.84M-word tail region holds (disjoint): ys16/yv16 (bf16, written by projdual,
// read by gc2all) and xsp/xvp (bf16 padded feats, written by padfeat, read by gc1all).
constexpr long long F_Y16    = F_XV1 + (long long)N_VENDOR * HID;          // words
constexpr long long F_PAD    = F_Y16 + 2000000;                  // ys16+yv16 use 1.92M words
constexpr long long F_END    = F_Y16 + 3840000;
static_assert(F_PAD + (long long)(N_SITE + N_VENDOR) * 16 / 2 <= F_END, "pads fit");
static_assert(BUILD_END < F_Y16, "pairs below bf16 tail region");
constexpr long long SHARED_END = (BUILD_END > F_END) ? BUILD_END : F_END;
constexpr long long F_FUSED  = SHARED_END;                       // [4352]
constexpr long long WS_WORDS = F_FUSED + 4352;                   // ~72.2 MB

// fused sub-offsets (layer-1 matrices padded to 16 rows; pad rows are ZERO)
constexpr int F_M1SV = 0;      // 16x64  W_site_in@Wl1sv   (rows 10..15 = 0)
constexpr int F_M1VS = 1024;   // 16x64  W_vendor_in@Wl1vs (rows 9..15 = 0)
constexpr int F_R1SV = 2048;   // 16x64  W_vendor_in@Wr1sv
constexpr int F_R1VS = 3072;   // 16x64  W_site_in@Wr1vs
constexpr int F_V1SV = 4096;   // 64     b_site_in@Wl1sv
constexpr int F_V1VS = 4160;   // 64     b_vendor_in@Wl1vs
constexpr int F_r1SV = 4224;   // 64     b_vendor_in@Wr1sv
constexpr int F_r1VS = 4288;   // 64     b_site_in@Wr1vs

// bf16 helpers
__device__ __forceinline__ unsigned short bfr(float f) {   // RNE pack
    unsigned u = __float_as_uint(f);
    return (unsigned short)((u + 0x7FFFu + ((u >> 16) & 1u)) >> 16);
}
__device__ __forceinline__ float bflo(unsigned u) { return __uint_as_float(u << 16); }
__device__ __forceinline__ float bfhi(unsigned u) { return __uint_as_float(u & 0xFFFF0000u); }
__device__ __forceinline__ float bfs(unsigned short v) { return __uint_as_float((unsigned)v << 16); }

// ---------------------------------------------------------------------------
// Fold input projection + layer-1 weights into padded fused matrices.
__global__ __launch_bounds__(256) void fuse_weights(
        const float* __restrict__ Wsi, const float* __restrict__ bsi,
        const float* __restrict__ Wvi, const float* __restrict__ bvi,
        const float* __restrict__ Wl1sv, const float* __restrict__ Wr1sv,
        const float* __restrict__ Wl1vs, const float* __restrict__ Wr1vs,
        float* __restrict__ fused) {
    int idx = blockIdx.x * 256 + threadIdx.x;
    if (idx < 4096) {                       // matrices, m = 0..3 (16x64 each)
        int m = idx >> 10, rem = idx & 1023, r = rem >> 6, c = rem & 63;
        int K = (m == 0 || m == 3) ? SITE_IN : VENDOR_IN;
        const float* A = (m == 0 || m == 3) ? Wsi : Wvi;
        const float* B = (m == 0) ? Wl1sv : (m == 1) ? Wl1vs : (m == 2) ? Wr1sv : Wr1vs;
        float s = 0.f;
        if (r < K)
            for (int j = 0; j < 64; ++j) s = fmaf(A[r * 64 + j], B[j * 64 + c], s);
        fused[idx] = s;
    } else if (idx < 4352) {                // bias vectors
        int m = (idx - 4096) >> 6, c = idx & 63;
        const float* a = (m == 0 || m == 3) ? bsi : bvi;
        const float* B = (m == 0) ? Wl1sv : (m == 1) ? Wl1vs : (m == 2) ? Wr1sv : Wr1vs;
        float s = 0.f;
        for (int j = 0; j < 64; ++j) s = fmaf(a[j], B[j * 64 + c], s);
        fused[idx] = s;
    }
}

// ---------------------------------------------------------------------------
// Pad raw features to 16 bf16/row (32 B, aligned) for vectorized gathers.
__global__ __launch_bounds__(256) void padfeat(const float* __restrict__ x_site,
                                               const float* __restrict__ x_vendor,
                                               unsigned short* __restrict__ xsp,
                                               unsigned short* __restrict__ xvp) {
    int t = blockIdx.x * 256 + threadIdx.x;
    if (t < N_SITE * 16) {
        int i = t >> 4, k = t & 15;
        xsp[t] = bfr(k < SITE_IN ? x_site[i * SITE_IN + k] : 0.f);
    } else {
        t -= N_SITE * 16;
        if (t < N_VENDOR * 16) {
            int i = t >> 4, k = t & 15;
            xvp[t] = bfr(k < VENDOR_IN ? x_vendor[i * VENDOR_IN + k] : 0.f);
        }
    }
}

// ---------------------------------------------------------------------------
// Build K1: per-block LDS bucket histograms for BOTH directions in one edge
// read. Writes private h2 rows (no atomics) + merges bucket totals.
__global__ __launch_bounds__(256) void histbk(const int* __restrict__ src,
                                              const int* __restrict__ dst,
                                              int* __restrict__ h2s,
                                              int* __restrict__ h2v,
                                              int* __restrict__ tot) {
    __shared__ int hs[NBUK_S];
    __shared__ int hv[NBUK_V];
    int blk = blockIdx.x, tid = threadIdx.x;
    for (int i = tid; i < NBUK_S; i += 256) hs[i] = 0;
    for (int i = tid; i < NBUK_V; i += 256) hv[i] = 0;
    __syncthreads();
    int lo = blk * EPB;
    for (int e = lo + tid; e < lo + EPB; e += 256) {
        atomicAdd(&hs[src[e] >> SHIFT_S], 1);
        atomicAdd(&hv[dst[e] >> SHIFT_V], 1);
    }
    __syncthreads();
    for (int i = tid; i < NBUK_S; i += 256) {
        int c = hs[i];
        h2s[(long long)blk * NBUK_S + i] = c;
        if (c) atomicAdd(&tot[i], c);
    }
    for (int i = tid; i < NBUK_V; i += 256) {
        int c = hv[i];
        h2v[(long long)blk * NBUK_V + i] = c;
        if (c) atomicAdd(&tot[NBUK_S + i], c);
    }
}

// Build K2: exclusive scan of bucket totals -> bucket base offsets.
__global__ __launch_bounds__(512) void basescan(const int* __restrict__ tot,
                                                int* __restrict__ base_s,
                                                int* __restrict__ base_v) {
    __shared__ int a[512];
    int tid = threadIdx.x;
    int v = (tid < NBUK_S) ? tot[tid] : 0;
    a[tid] = v; __syncthreads();
    for (int st = 1; st < 512; st <<= 1) {
        int x = (tid >= st) ? a[tid - st] : 0; __syncthreads();
        a[tid] += x; __syncthreads();
    }
    if (tid < NBUK_S) base_s[tid] = a[tid] - v;
    if (tid == 0) base_s[NBUK_S] = NE;
    __syncthreads();
    int w = (tid < NBUK_V) ? tot[NBUK_S + tid] : 0;
    a[tid] = w; __syncthreads();
    for (int st = 1; st < 512; st <<= 1) {
        int x = (tid >= st) ? a[tid - st] : 0; __syncthreads();
        a[tid] += x; __syncthreads();
    }
    if (tid < NBUK_V) base_v[tid] = a[tid] - w;
    if (tid == 0) base_v[NBUK_V] = NE;
}

// Build K3: convert h2 counts into per-(chunk,bucket) write cursors.
__global__ __launch_bounds__(256) void cursorize(int* __restrict__ h2s,
                                                 int* __restrict__ h2v,
                                                 const int* __restrict__ base_s,
                                                 const int* __restrict__ base_v) {
    int b = blockIdx.x, tid = threadIdx.x;
    int* h2; const int* base; int nbuk;
    if (b < NBUK_S) { h2 = h2s; base = base_s; nbuk = NBUK_S; }
    else            { b -= NBUK_S; h2 = h2v; base = base_v; nbuk = NBUK_V; }
    int c[4], loc[4], s = 0;
    #pragma unroll
    for (int i = 0; i < 4; ++i) c[i] = h2[(long long)(tid * 4 + i) * nbuk + b];
    #pragma unroll
    for (int i = 0; i < 4; ++i) { loc[i] = s; s += c[i]; }
    __shared__ int p[256];
    p[tid] = s; __syncthreads();
    for (int st = 1; st < 256; st <<= 1) {
        int x = (tid >= st) ? p[tid - st] : 0; __syncthreads();
        p[tid] += x; __syncthreads();
    }
    int pre = base[b] + (tid ? p[tid - 1] : 0);
    #pragma unroll
    for (int i = 0; i < 4; ++i) h2[(long long)(tid * 4 + i) * nbuk + b] = pre + loc[i];
}

// Build K4: pass-1 scatter of (key,val) pairs into bucket-grouped order.
template<int NBUK, int SHIFT>
__global__ __launch_bounds__(256) void scatter1(const int* __restrict__ key,
                                                const int* __restrict__ val,
                                                const int* __restrict__ h2,
                                                int2* __restrict__ pairs) {
    __shared__ int cur[NBUK];
    int blk = blockIdx.x, tid = threadIdx.x;
    for (int i = tid; i < NBUK; i += 256) cur[i] = h2[(long long)blk * NBUK + i];
    __syncthreads();
    int lo = blk * EPB;
    for (int e = lo + tid; e < lo + EPB; e += 256) {
        int k = key[e];
        int p = atomicAdd(&cur[k >> SHIFT], 1);
        pairs[p] = make_int2(k, val[e]);
    }
}

// Build K5: pass-2 per-bucket counting sort into the bucket's contiguous
// (L2-hot) adj region; coalesced off[] write.
template<int BW, int SHIFT>
__global__ __launch_bounds__(256) void stage2(const int2* __restrict__ pairs,
                                              const int* __restrict__ base,
                                              int* __restrict__ off,
                                              int* __restrict__ adj,
                                              int nnode, int nbuk) {
    int b = blockIdx.x, tid = threadIdx.x;
    int lo_node = b << SHIFT;
    int p0 = base[b], p1 = base[b + 1];
    __shared__ int deg[BW];
    __shared__ int cur[BW];
    __shared__ int sc[256];
    if (tid < BW) deg[tid] = 0;
    __syncthreads();
    for (int e = p0 + tid; e < p1; e += 256)
        atomicAdd(&deg[pairs[e].x - lo_node], 1);
    __syncthreads();
    int d = (tid < BW) ? deg[tid] : 0;
    sc[tid] = d;
    __syncthreads();
    for (int st = 1; st < 256; st <<= 1) {
        int x = (tid >= st) ? sc[tid - st] : 0; __syncthreads();
        sc[tid] += x; __syncthreads();
    }
    int excl = sc[tid] - d;
    if (tid < BW) {
        int node = lo_node + tid;
        if (node < nnode) off[node] = p0 + excl;
        cur[tid] = p0 + excl;
    }
    if (b == nbuk - 1 && tid == 0) off[nnode] = NE;
    __syncthreads();
    for (int e = p0 + tid; e < p1; e += 256) {
        int2 pr = pairs[e];
        int p = atomicAdd(&cur[pr.x - lo_node], 1);
        adj[p] = pr.y;
    }
}

// ---------------------------------------------------------------------------
// Merged fused layer-1 for both directions: per-node gather of padded 16-slot
// bf16 neighbor rows (uint4 + uint = 20 B of a 32 B row) + mean-project +
// fp32 self-project + biases + relu. One wave per node.
__global__ __launch_bounds__(256) void gc1all(
        const unsigned short* __restrict__ xsp, const unsigned short* __restrict__ xvp,
        const float* __restrict__ xs_raw, const float* __restrict__ xv_raw,
        const int* __restrict__ off_s, const int* __restrict__ adj_s,
        const int* __restrict__ off_v, const int* __restrict__ adj_v,
        const float* __restrict__ fused,
        const float* __restrict__ bl1vs, const float* __restrict__ bl1sv,
        float* __restrict__ xs1, float* __restrict__ xv1) {
    int b = blockIdx.x;
    const unsigned short* fp;
    const float *fsraw, *M, *V, *BL, *R, *RV;
    const int *off, *adj;
    float* xout; int w, n, kx;
    if (b < SB1) {       // site node: aggregate vendor feats, self = site feats
        w = b * 4 + (threadIdx.x >> 6); n = N_SITE; kx = SITE_IN;
        fp = xvp; fsraw = xs_raw; off = off_s; adj = adj_s;
        M = fused + F_M1VS; V = fused + F_V1VS; BL = bl1vs;
        R = fused + F_R1VS; RV = fused + F_r1VS;
        xout = xs1;
    } else {             // vendor node
        w = (b - SB1) * 4 + (threadIdx.x >> 6); n = N_VENDOR; kx = VENDOR_IN;
        fp = xsp; fsraw = xv_raw; off = off_v; adj = adj_v;
        M = fused + F_M1SV; V = fused + F_V1SV; BL = bl1sv;
        R = fused + F_R1SV; RV = fused + F_r1SV;
        xout = xv1;
    }
    int lane = threadIdx.x & 63;
    if (w >= n) return;
    int lo = off[w], hi = off[w + 1], deg = hi - lo;
    float s[10];
    #pragma unroll
    for (int k = 0; k < 10; ++k) s[k] = 0.f;
    for (int j = lo + lane; j < hi; j += 64) {
        const unsigned short* row = fp + (long long)adj[j] * 16;
        uint4 q0 = *(const uint4*)row;
        unsigned u4 = *(const unsigned*)(row + 8);
        s[0] += bflo(q0.x); s[1] += bfhi(q0.x);
        s[2] += bflo(q0.y); s[3] += bfhi(q0.y);
        s[4] += bflo(q0.z); s[5] += bfhi(q0.z);
        s[6] += bflo(q0.w); s[7] += bfhi(q0.w);
        s[8] += bflo(u4);   s[9] += bfhi(u4);
    }
    #pragma unroll
    for (int k = 0; k < 10; ++k) {
        #pragma unroll
        for (int m = 32; m >= 1; m >>= 1) s[k] += __shfl_xor(s[k], m, 64);
    }
    float inv = 1.0f / (float)max(deg, 1);
    float acc = BL[lane] + RV[lane] + (deg > 0 ? V[lane] : 0.f);
    #pragma unroll
    for (int k = 0; k < 10; ++k) acc = fmaf(s[k] * inv, M[k * 64 + lane], acc);
    const float* xr = fsraw + (long long)w * kx;     // broadcast fp32 self row
    for (int k = 0; k < kx; ++k) acc = fmaf(xr[k], R[k * 64 + lane], acc);
    xout[(long long)w * 64 + lane] = fmaxf(acc, 0.f);
}

// ---------------------------------------------------------------------------
// Merged dual projection (register-tiled mini-GEMM):
//   [y | z] = X1[n,64] @ [Wl2 | Wr2]
// y (cols 0..31) -> BF16 ys/yv scratch (gathered by the other side's gc2);
// z (cols 32..63) -> fp32, DIRECTLY into d_out (self term; gc2 RMWs it).
__global__ __launch_bounds__(256) void projdual(
        const float* __restrict__ xs1, const float* __restrict__ xv1,
        const float* __restrict__ Wl2sv, const float* __restrict__ Wr2vs,
        const float* __restrict__ Wl2vs, const float* __restrict__ Wr2sv,
        unsigned short* __restrict__ ys16, unsigned short* __restrict__ yv16,
        float* __restrict__ out) {
    __shared__ float sW[64 * 64];
    __shared__ float sX[64 * 65];   // +1 pad: conflict-free column reads
    int b = blockIdx.x, tid = threadIdx.x;
    const float *X, *Wl, *Wr; unsigned short* Y; float* Z; int base, n;
    if (b < PD_S) {
        base = b * 64; n = N_SITE; X = xs1;
        Wl = Wl2sv; Wr = Wr2vs; Y = ys16; Z = out;
    } else {
        base = (b - PD_S) * 64; n = N_VENDOR; X = xv1;
        Wl = Wl2vs; Wr = Wr2sv; Y = yv16; Z = out + (long long)N_SITE * OUT;
    }
    for (int i = tid; i < 4096; i += 256) {
        int k = i >> 6, c = i & 63;
        sW[i] = (c < 32) ? Wl[k * 32 + c] : Wr[k * 32 + (c - 32)];
    }
    for (int i = tid; i < 4096; i += 256) {
        int r = i >> 6, c = i & 63;
        int node = base + r;
        sX[r * 65 + c] = (node < n) ? X[(long long)node * 64 + c] : 0.f;
    }
    __syncthreads();
    int ng = tid >> 4, cg = tid & 15;     // 4-node group, 4-col group
    float acc[4][4] = {};
    for (int k = 0; k < 64; ++k) {
        float4 w4 = *(const float4*)(sW + k * 64 + cg * 4);
        #pragma unroll
        for (int i = 0; i < 4; ++i) {
            float xv = sX[(ng * 4 + i) * 65 + k];
            acc[i][0] = fmaf(xv, w4.x, acc[i][0]);
            acc[i][1] = fmaf(xv, w4.y, acc[i][1]);
            acc[i][2] = fmaf(xv, w4.z, acc[i][2]);
            acc[i][3] = fmaf(xv, w4.w, acc[i][3]);
        }
    }
    #pragma unroll
    for (int i = 0; i < 4; ++i) {
        int node = base + ng * 4 + i;
        if (node >= n) continue;
        if (cg < 8) {
            unsigned p01 = (unsigned)bfr(acc[i][0]) | ((unsigned)bfr(acc[i][1]) << 16);
            unsigned p23 = (unsigned)bfr(acc[i][2]) | ((unsigned)bfr(acc[i][3]) << 16);
            *(uint2*)(Y + (long long)node * 32 + cg * 4) = make_uint2(p01, p23);
        } else {
            *(float4*)(Z + (long long)node * 32 + (cg - 8) * 4) =
                make_float4(acc[i][0], acc[i][1], acc[i][2], acc[i][3]);
        }
    }
}

// ---------------------------------------------------------------------------
// Merged layer-2 combine: out = relu(gather_mean(bf16 y) + b + z) where z was
// pre-written into d_out by projdual. One wave per node; lanes = 2 edges x 32
// cols; gather unrolled x4 for MLP.
__global__ __launch_bounds__(256) void gc2all(
        const unsigned short* __restrict__ ys16, const unsigned short* __restrict__ yv16,
        const int* __restrict__ off_s, const int* __restrict__ adj_s,
        const int* __restrict__ off_v, const int* __restrict__ adj_v,
        const float* __restrict__ bl2vs, const float* __restrict__ bl2sv,
        float* __restrict__ out) {
    int b = blockIdx.x;
    const unsigned short* y; const float* bias; const int *off, *adj;
    float* o; int w, n;
    if (b < SB1) {       // site outputs gather vendor pre-projections
        w = b * 4 + (threadIdx.x >> 6); n = N_SITE;
        y = yv16; off = off_s; adj = adj_s; bias = bl2vs; o = out;
    } else {
        w = (b - SB1) * 4 + (threadIdx.x >> 6); n = N_VENDOR;
        y = ys16; off = off_v; adj = adj_v; bias = bl2sv;
        o = out + (long long)N_SITE * OUT;
    }
    if (w >= n) return;
    int lane = threadIdx.x & 63, c = lane & 31, g = lane >> 5;
    int lo = off[w], hi = off[w + 1], deg = hi - lo;
    int m = (deg > g) ? ((deg - g + 1) >> 1) : 0;   // edges for this lane-group
    const int* ap = adj + lo + g;
    float s = 0.f;
    int t = 0;
    for (; t + 4 <= m; t += 4) {
        int a0 = ap[2 * t], a1 = ap[2 * t + 2], a2 = ap[2 * t + 4], a3 = ap[2 * t + 6];
        s += bfs(y[(long long)a0 * 32 + c]);
        s += bfs(y[(long long)a1 * 32 + c]);
        s += bfs(y[(long long)a2 * 32 + c]);
        s += bfs(y[(long long)a3 * 32 + c]);
    }
    for (; t < m; ++t) s += bfs(y[(long long)ap[2 * t] * 32 + c]);
    s += __shfl_xor(s, 32, 64);
    if (g == 0) {
        float inv = 1.0f / (float)max(deg, 1);
        long long oi = (long long)w * 32 + c;
        o[oi] = fmaxf(fmaf(s, inv, bias[c] + o[oi]), 0.f);
    }
}

// ---------------------------------------------------------------------------
extern "C" void kernel_launch(void* const* d_in, const int* in_sizes, int n_in,
                              void* d_out, int out_size, void* d_ws, size_t ws_size,
                              hipStream_t stream) {
    const float* x_site      = (const float*)d_in[0];
    const float* x_vendor    = (const float*)d_in[1];
    const int*   src         = (const int*)d_in[2];
    const int*   dst         = (const int*)d_in[3];
    const float* W_site_in   = (const float*)d_in[4];
    const float* b_site_in   = (const float*)d_in[5];
    const float* W_vendor_in = (const float*)d_in[6];
    const float* b_vendor_in = (const float*)d_in[7];
    const float* Wl1sv = (const float*)d_in[8];
    const float* bl1sv = (const float*)d_in[9];
    const float* Wr1sv = (const float*)d_in[10];
    const float* Wl1vs = (const float*)d_in[11];
    const float* bl1vs = (const float*)d_in[12];
    const float* Wr1vs = (const float*)d_in[13];
    const float* Wl2sv = (const float*)d_in[14];
    const float* bl2sv = (const float*)d_in[15];
    const float* Wr2sv = (const float*)d_in[16];
    const float* Wl2vs = (const float*)d_in[17];
    const float* bl2vs = (const float*)d_in[18];
    const float* Wr2vs = (const float*)d_in[19];

    // Guard: never write past harness scratch (overrun can kill the container).
    if (ws_size < (size_t)WS_WORDS * 4) return;

    int*   wi  = (int*)d_ws;
    float* wf  = (float*)d_ws;
    float* out = (float*)d_out;

    int* off_v  = wi + I_OFF_V;
    int* off_s  = wi + I_OFF_S;
    int* base_s = wi + I_BASE_S;
    int* base_v = wi + I_BASE_V;
    int* tot    = wi + I_TOT;
    int* adj_v  = wi + I_ADJ_V;
    int* adj_s  = wi + I_ADJ_S;
    int* h2s    = wi + A_H2S;     // aliases float region (floats written post-build)
    int* h2v    = wi + A_H2V;
    int2* pairs = (int2*)(wi + A_PAIRS);
    float* xs1   = wf + F_XS1;
    float* xv1   = wf + F_XV1;
    unsigned short* ys16 = (unsigned short*)(wf + F_Y16);
    unsigned short* yv16 = ys16 + (long long)N_SITE * OUT;
    unsigned short* xsp  = (unsigned short*)(wf + F_PAD);
    unsigned short* xvp  = xsp + (long long)N_SITE * 16;
    float* fused = wf + F_FUSED;

    // zero bucket totals (ws not re-poisoned between replays; zero every call)
    hipMemsetAsync(tot, 0, (size_t)(NBUK_S + NBUK_V) * sizeof(int), stream);

    fuse_weights<<<17, 256, 0, stream>>>(W_site_in, b_site_in, W_vendor_in, b_vendor_in,
                                         Wl1sv, Wr1sv, Wl1vs, Wr1vs, fused);
    padfeat<<<(16 * (N_SITE + N_VENDOR) + 255) / 256, 256, 0, stream>>>(
        x_site, x_vendor, xsp, xvp);

    // --- CSR build: two-level radix, all scatters L2-absorbed ---
    histbk<<<NBLK, 256, 0, stream>>>(src, dst, h2s, h2v, tot);
    basescan<<<1, 512, 0, stream>>>(tot, base_s, base_v);
    cursorize<<<NBUK_S + NBUK_V, 256, 0, stream>>>(h2s, h2v, base_s, base_v);
    scatter1<NBUK_S, SHIFT_S><<<NBLK, 256, 0, stream>>>(src, dst, h2s, pairs);
    stage2<256, SHIFT_S><<<NBUK_S, 256, 0, stream>>>(pairs, base_s, off_s, adj_s,
                                                     N_SITE, NBUK_S);
    scatter1<NBUK_V, SHIFT_V><<<NBLK, 256, 0, stream>>>(dst, src, h2v, pairs);
    stage2<128, SHIFT_V><<<NBUK_V, 256, 0, stream>>>(pairs, base_v, off_v, adj_v,
                                                     N_VENDOR, NBUK_V);

    // --- layer 1: merged fused gather+project+self+relu (both directions) ---
    gc1all<<<SB1 + VB1, 256, 0, stream>>>(xsp, xvp, x_site, x_vendor,
                                          off_s, adj_s, off_v, adj_v,
                                          fused, bl1vs, bl1sv, xs1, xv1);

    // --- layer 2 pre-projections (bf16) + self terms (fp32 into d_out) ---
    projdual<<<PD_S + PD_V, 256, 0, stream>>>(xs1, xv1, Wl2sv, Wr2vs, Wl2vs, Wr2sv,
                                              ys16, yv16, out);

    // --- layer 2: merged gather+mean+bias+self+relu ---
    gc2all<<<SB1 + VB1, 256, 0, stream>>>(ys16, yv16, off_s, adj_s, off_v, adj_v,
                                          bl2vs, bl2sv, out);

    (void)in_sizes; (void)n_in; (void)out_size;
}

// Round 8
// 394.578 us; speedup vs baseline: 10.4812x; 1.1360x over previous
//
#include <hip/hip_runtime.h>

// Problem constants
constexpr int N_SITE    = 100000;
constexpr int N_VENDOR  = 20000;
constexpr int NE        = 3200000;
constexpr int SITE_IN   = 10;
constexpr int VENDOR_IN = 9;
constexpr int HID       = 64;
constexpr int OUT       = 32;

// Radix-build parameters
constexpr int NBLK    = 1024;            // pass-1 grid (each block = one chunk)
constexpr int EPB     = NE / NBLK;       // 3125 edges per block
constexpr int SHIFT_S = 8;               // 256 sites per bucket
constexpr int NBUK_S  = (N_SITE + 255) / 256;    // 391
constexpr int SHIFT_V = 7;               // 128 vendors per bucket
constexpr int NBUK_V  = (N_VENDOR + 127) / 128;  // 157

// Merged-launch block ranges
constexpr int SB1  = (N_SITE + 3) / 4;           // 25000 (gc1/gc2 site blocks)
constexpr int VB1  = (N_VENDOR + 3) / 4;         // 5000
constexpr int PD_S = (N_SITE + 63) / 64;         // 1563 (projdual site blocks)
constexpr int PD_V = (N_VENDOR + 63) / 64;       // 313

// ---------------------------------------------------------------------------
// Workspace layout (4-byte words).
constexpr long long I_OFF_V  = 0;                                // [N_VENDOR+1]
constexpr long long I_OFF_S  = I_OFF_V + N_VENDOR + 1;           // [N_SITE+1]
constexpr long long I_BASE_S = I_OFF_S + N_SITE + 1;             // [NBUK_S+1]
constexpr long long I_BASE_V = I_BASE_S + NBUK_S + 1;            // [NBUK_V+1]
constexpr long long I_TOT    = I_BASE_V + NBUK_V + 1;            // [NBUK_S+NBUK_V] zeroed/call
constexpr long long I_ADJ_V  = I_TOT + NBUK_S + NBUK_V;          // [NE] int
constexpr long long I_ADJ_S  = I_ADJ_V + NE;                     // [NE/2] words as u16[NE]
constexpr long long INT_END  = I_ADJ_S + NE;                     // (slot kept NE words)
// Build scratch (h2 cursor tables + packed pairs) aliases the float
// intermediates: floats are only written after the build completes.
constexpr long long A_H2S    = INT_END;                          // [NBLK*NBUK_S]
constexpr long long A_H2V    = A_H2S + (long long)NBLK * NBUK_S; // [NBLK*NBUK_V]
constexpr long long A_PAIRS  = (A_H2V + (long long)NBLK * NBUK_V + 1) & ~1LL;
constexpr long long BUILD_END = A_PAIRS + 2LL * NE;              // pairs_s + pairs_v (u32 each)
constexpr long long F_XS1    = INT_END;                          // [100000*64] fp32
constexpr long long F_XV1    = F_XS1 + (long long)N_SITE * HID;  // [20000*64]  fp32
// 3.84M-word tail: ys16/yv16 (bf16, projdual->gc2all) and xsp/xvp (bf16 padded
// feats, padfeat->gc1all). Disjoint from pairs (assert below).
constexpr long long F_Y16    = F_XV1 + (long long)N_VENDOR * HID;
constexpr long long F_PAD    = F_Y16 + 2000000;                  // ys16+yv16 = 1.92M words
constexpr long long F_END    = F_Y16 + 3840000;
static_assert(F_PAD + (long long)(N_SITE + N_VENDOR) * 16 / 2 <= F_END, "pads fit");
static_assert(BUILD_END < F_Y16, "pairs below bf16 tail region");
constexpr long long SHARED_END = (BUILD_END > F_END) ? BUILD_END : F_END;
constexpr long long F_FUSED  = SHARED_END;                       // [4352]
constexpr long long WS_WORDS = F_FUSED + 4352;                   // ~72.2 MB

// fused sub-offsets (layer-1 matrices padded to 16 rows; pad rows are ZERO)
constexpr int F_M1SV = 0;      // 16x64  W_site_in@Wl1sv   (rows 10..15 = 0)
constexpr int F_M1VS = 1024;   // 16x64  W_vendor_in@Wl1vs (rows 9..15 = 0)
constexpr int F_R1SV = 2048;   // 16x64  W_vendor_in@Wr1sv
constexpr int F_R1VS = 3072;   // 16x64  W_site_in@Wr1vs
constexpr int F_V1SV = 4096;   // 64     b_site_in@Wl1sv
constexpr int F_V1VS = 4160;   // 64     b_vendor_in@Wl1vs
constexpr int F_r1SV = 4224;   // 64     b_vendor_in@Wr1sv
constexpr int F_r1VS = 4288;   // 64     b_site_in@Wr1vs

// bf16 helpers
__device__ __forceinline__ unsigned short bfr(float f) {   // RNE pack
    unsigned u = __float_as_uint(f);
    return (unsigned short)((u + 0x7FFFu + ((u >> 16) & 1u)) >> 16);
}
__device__ __forceinline__ float bflo(unsigned u) { return __uint_as_float(u << 16); }
__device__ __forceinline__ float bfhi(unsigned u) { return __uint_as_float(u & 0xFFFF0000u); }

// ---------------------------------------------------------------------------
// Fold input projection + layer-1 weights into padded fused matrices.
__global__ __launch_bounds__(256) void fuse_weights(
        const float* __restrict__ Wsi, const float* __restrict__ bsi,
        const float* __restrict__ Wvi, const float* __restrict__ bvi,
        const float* __restrict__ Wl1sv, const float* __restrict__ Wr1sv,
        const float* __restrict__ Wl1vs, const float* __restrict__ Wr1vs,
        float* __restrict__ fused) {
    int idx = blockIdx.x * 256 + threadIdx.x;
    if (idx < 4096) {                       // matrices, m = 0..3 (16x64 each)
        int m = idx >> 10, rem = idx & 1023, r = rem >> 6, c = rem & 63;
        int K = (m == 0 || m == 3) ? SITE_IN : VENDOR_IN;
        const float* A = (m == 0 || m == 3) ? Wsi : Wvi;
        const float* B = (m == 0) ? Wl1sv : (m == 1) ? Wl1vs : (m == 2) ? Wr1sv : Wr1vs;
        float s = 0.f;
        if (r < K)
            for (int j = 0; j < 64; ++j) s = fmaf(A[r * 64 + j], B[j * 64 + c], s);
        fused[idx] = s;
    } else if (idx < 4352) {                // bias vectors
        int m = (idx - 4096) >> 6, c = idx & 63;
        const float* a = (m == 0 || m == 3) ? bsi : bvi;
        const float* B = (m == 0) ? Wl1sv : (m == 1) ? Wl1vs : (m == 2) ? Wr1sv : Wr1vs;
        float s = 0.f;
        for (int j = 0; j < 64; ++j) s = fmaf(a[j], B[j * 64 + c], s);
        fused[idx] = s;
    }
}

// ---------------------------------------------------------------------------
// Pad raw features to 16 bf16/row (32 B, aligned) for vectorized gathers.
__global__ __launch_bounds__(256) void padfeat(const float* __restrict__ x_site,
                                               const float* __restrict__ x_vendor,
                                               unsigned short* __restrict__ xsp,
                                               unsigned short* __restrict__ xvp) {
    int t = blockIdx.x * 256 + threadIdx.x;
    if (t < N_SITE * 16) {
        int i = t >> 4, k = t & 15;
        xsp[t] = bfr(k < SITE_IN ? x_site[i * SITE_IN + k] : 0.f);
    } else {
        t -= N_SITE * 16;
        if (t < N_VENDOR * 16) {
            int i = t >> 4, k = t & 15;
            xvp[t] = bfr(k < VENDOR_IN ? x_vendor[i * VENDOR_IN + k] : 0.f);
        }
    }
}

// ---------------------------------------------------------------------------
// Build K1: per-block LDS bucket histograms for BOTH directions in one edge
// read. Writes private h2 rows (no atomics) + merges bucket totals.
__global__ __launch_bounds__(256) void histbk(const int* __restrict__ src,
                                              const int* __restrict__ dst,
                                              int* __restrict__ h2s,
                                              int* __restrict__ h2v,
                                              int* __restrict__ tot) {
    __shared__ int hs[NBUK_S];
    __shared__ int hv[NBUK_V];
    int blk = blockIdx.x, tid = threadIdx.x;
    for (int i = tid; i < NBUK_S; i += 256) hs[i] = 0;
    for (int i = tid; i < NBUK_V; i += 256) hv[i] = 0;
    __syncthreads();
    int lo = blk * EPB;
    for (int e = lo + tid; e < lo + EPB; e += 256) {
        atomicAdd(&hs[src[e] >> SHIFT_S], 1);
        atomicAdd(&hv[dst[e] >> SHIFT_V], 1);
    }
    __syncthreads();
    for (int i = tid; i < NBUK_S; i += 256) {
        int c = hs[i];
        h2s[(long long)blk * NBUK_S + i] = c;
        if (c) atomicAdd(&tot[i], c);
    }
    for (int i = tid; i < NBUK_V; i += 256) {
        int c = hv[i];
        h2v[(long long)blk * NBUK_V + i] = c;
        if (c) atomicAdd(&tot[NBUK_S + i], c);
    }
}

// Build K2: exclusive scan of bucket totals -> bucket base offsets.
__global__ __launch_bounds__(512) void basescan(const int* __restrict__ tot,
                                                int* __restrict__ base_s,
                                                int* __restrict__ base_v) {
    __shared__ int a[512];
    int tid = threadIdx.x;
    int v = (tid < NBUK_S) ? tot[tid] : 0;
    a[tid] = v; __syncthreads();
    for (int st = 1; st < 512; st <<= 1) {
        int x = (tid >= st) ? a[tid - st] : 0; __syncthreads();
        a[tid] += x; __syncthreads();
    }
    if (tid < NBUK_S) base_s[tid] = a[tid] - v;
    if (tid == 0) base_s[NBUK_S] = NE;
    __syncthreads();
    int w = (tid < NBUK_V) ? tot[NBUK_S + tid] : 0;
    a[tid] = w; __syncthreads();
    for (int st = 1; st < 512; st <<= 1) {
        int x = (tid >= st) ? a[tid - st] : 0; __syncthreads();
        a[tid] += x; __syncthreads();
    }
    if (tid < NBUK_V) base_v[tid] = a[tid] - w;
    if (tid == 0) base_v[NBUK_V] = NE;
}

// Build K3: convert h2 counts into per-(chunk,bucket) write cursors.
__global__ __launch_bounds__(256) void cursorize(int* __restrict__ h2s,
                                                 int* __restrict__ h2v,
                                                 const int* __restrict__ base_s,
                                                 const int* __restrict__ base_v) {
    int b = blockIdx.x, tid = threadIdx.x;
    int* h2; const int* base; int nbuk;
    if (b < NBUK_S) { h2 = h2s; base = base_s; nbuk = NBUK_S; }
    else            { b -= NBUK_S; h2 = h2v; base = base_v; nbuk = NBUK_V; }
    int c[4], loc[4], s = 0;
    #pragma unroll
    for (int i = 0; i < 4; ++i) c[i] = h2[(long long)(tid * 4 + i) * nbuk + b];
    #pragma unroll
    for (int i = 0; i < 4; ++i) { loc[i] = s; s += c[i]; }
    __shared__ int p[256];
    p[tid] = s; __syncthreads();
    for (int st = 1; st < 256; st <<= 1) {
        int x = (tid >= st) ? p[tid - st] : 0; __syncthreads();
        p[tid] += x; __syncthreads();
    }
    int pre = base[b] + (tid ? p[tid - 1] : 0);
    #pragma unroll
    for (int i = 0; i < 4; ++i) h2[(long long)(tid * 4 + i) * nbuk + b] = pre + loc[i];
}

// Build K4: scatter PACKED 4-byte pairs for BOTH directions in one edge read.
// site pair:   (site&255)<<24 | vendor   (vendor < 2^15)
// vendor pair: (vendor&127)<<25 | site   (site < 2^17)
__global__ __launch_bounds__(256) void scatter_both(
        const int* __restrict__ src, const int* __restrict__ dst,
        const int* __restrict__ h2s, const int* __restrict__ h2v,
        unsigned* __restrict__ pairs_s, unsigned* __restrict__ pairs_v) {
    __shared__ int cs[NBUK_S];
    __shared__ int cv[NBUK_V];
    int blk = blockIdx.x, tid = threadIdx.x;
    for (int i = tid; i < NBUK_S; i += 256) cs[i] = h2s[(long long)blk * NBUK_S + i];
    for (int i = tid; i < NBUK_V; i += 256) cv[i] = h2v[(long long)blk * NBUK_V + i];
    __syncthreads();
    int lo = blk * EPB;
    for (int e = lo + tid; e < lo + EPB; e += 256) {
        int s = src[e], d = dst[e];
        int ps = atomicAdd(&cs[s >> SHIFT_S], 1);
        pairs_s[ps] = ((unsigned)(s & 255) << 24) | (unsigned)d;
        int pv = atomicAdd(&cv[d >> SHIFT_V], 1);
        pairs_v[pv] = ((unsigned)(d & 127) << 25) | (unsigned)s;
    }
}

// Build K5: per-bucket counting sort for BOTH directions (grid-split).
// One block per bucket: LDS degree hist + scan -> coalesced off[] write +
// scatter into the bucket's contiguous (L2-hot) adj region.
__global__ __launch_bounds__(256) void stage2both(
        const unsigned* __restrict__ pairs_s, const unsigned* __restrict__ pairs_v,
        const int* __restrict__ base_s, const int* __restrict__ base_v,
        int* __restrict__ off_s, int* __restrict__ off_v,
        unsigned short* __restrict__ adj_s16, int* __restrict__ adj_v) {
    int b = blockIdx.x, tid = threadIdx.x;
    bool site = (b < NBUK_S);
    const unsigned* pairs; const int* base; int* off;
    int BW, nnode, shloc, lo_node;
    if (site) {
        pairs = pairs_s; base = base_s; off = off_s;
        BW = 256; nnode = N_SITE; shloc = 24; lo_node = b << SHIFT_S;
    } else {
        b -= NBUK_S;
        pairs = pairs_v; base = base_v; off = off_v;
        BW = 128; nnode = N_VENDOR; shloc = 25; lo_node = b << SHIFT_V;
    }
    int p0 = base[b], p1 = base[b + 1];
    __shared__ int deg[256];
    __shared__ int cur[256];
    __shared__ int sc[256];
    if (tid < BW) deg[tid] = 0;
    __syncthreads();
    for (int e = p0 + tid; e < p1; e += 256)
        atomicAdd(&deg[(int)(pairs[e] >> shloc)], 1);
    __syncthreads();
    int d = (tid < BW) ? deg[tid] : 0;
    sc[tid] = d;
    __syncthreads();
    for (int st = 1; st < 256; st <<= 1) {
        int x = (tid >= st) ? sc[tid - st] : 0; __syncthreads();
        sc[tid] += x; __syncthreads();
    }
    int excl = sc[tid] - d;
    if (tid < BW) {
        int node = lo_node + tid;
        if (node < nnode) off[node] = p0 + excl;
        cur[tid] = p0 + excl;
    }
    if (tid == 0) {
        if (site && b == NBUK_S - 1) off_s[N_SITE] = NE;
        if (!site && b == NBUK_V - 1) off_v[N_VENDOR] = NE;
    }
    __syncthreads();
    if (site) {
        for (int e = p0 + tid; e < p1; e += 256) {
            unsigned p = pairs[e];
            int pos = atomicAdd(&cur[(int)(p >> 24)], 1);
            adj_s16[pos] = (unsigned short)p;           // vendor id < 2^15
        }
    } else {
        for (int e = p0 + tid; e < p1; e += 256) {
            unsigned p = pairs[e];
            int pos = atomicAdd(&cur[(int)(p >> 25)], 1);
            adj_v[pos] = (int)(p & 0x1FFFFFFu);         // site id < 2^17
        }
    }
}

// ---------------------------------------------------------------------------
// Layer-1 gather helper (templated on adjacency index type).
template<typename IdxT>
__device__ __forceinline__ void gather1(const unsigned short* __restrict__ fp,
                                        const IdxT* __restrict__ adj,
                                        int lo, int hi, int lane, float* s) {
    for (int j = lo + lane; j < hi; j += 64) {
        const unsigned short* row = fp + (long long)adj[j] * 16;
        uint4 q0 = *(const uint4*)row;
        unsigned u4 = *(const unsigned*)(row + 8);
        s[0] += bflo(q0.x); s[1] += bfhi(q0.x);
        s[2] += bflo(q0.y); s[3] += bfhi(q0.y);
        s[4] += bflo(q0.z); s[5] += bfhi(q0.z);
        s[6] += bflo(q0.w); s[7] += bfhi(q0.w);
        s[8] += bflo(u4);   s[9] += bfhi(u4);
    }
}

// Merged fused layer-1 for both directions: per-node gather of padded 16-slot
// bf16 neighbor rows + mean-project + fp32 self-project + biases + relu.
// One wave per node.
__global__ __launch_bounds__(256) void gc1all(
        const unsigned short* __restrict__ xsp, const unsigned short* __restrict__ xvp,
        const float* __restrict__ xs_raw, const float* __restrict__ xv_raw,
        const int* __restrict__ off_s, const unsigned short* __restrict__ adj_s16,
        const int* __restrict__ off_v, const int* __restrict__ adj_v,
        const float* __restrict__ fused,
        const float* __restrict__ bl1vs, const float* __restrict__ bl1sv,
        float* __restrict__ xs1, float* __restrict__ xv1) {
    int b = blockIdx.x;
    bool site = (b < SB1);
    const float *fsraw, *M, *V, *BL, *R, *RV;
    const int* off;
    float* xout; int w, n, kx;
    if (site) {          // site node: aggregate vendor feats, self = site feats
        w = b * 4 + (threadIdx.x >> 6); n = N_SITE; kx = SITE_IN;
        fsraw = xs_raw; off = off_s;
        M = fused + F_M1VS; V = fused + F_V1VS; BL = bl1vs;
        R = fused + F_R1VS; RV = fused + F_r1VS;
        xout = xs1;
    } else {             // vendor node
        w = (b - SB1) * 4 + (threadIdx.x >> 6); n = N_VENDOR; kx = VENDOR_IN;
        fsraw = xv_raw; off = off_v;
        M = fused + F_M1SV; V = fused + F_V1SV; BL = bl1sv;
        R = fused + F_R1SV; RV = fused + F_r1SV;
        xout = xv1;
    }
    int lane = threadIdx.x & 63;
    if (w >= n) return;
    int lo = off[w], hi = off[w + 1], deg = hi - lo;
    float s[10];
    #pragma unroll
    for (int k = 0; k < 10; ++k) s[k] = 0.f;
    if (site) gather1(xvp, adj_s16, lo, hi, lane, s);
    else      gather1(xsp, adj_v,   lo, hi, lane, s);
    #pragma unroll
    for (int k = 0; k < 10; ++k) {
        #pragma unroll
        for (int m = 32; m >= 1; m >>= 1) s[k] += __shfl_xor(s[k], m, 64);
    }
    float inv = 1.0f / (float)max(deg, 1);
    float acc = BL[lane] + RV[lane] + (deg > 0 ? V[lane] : 0.f);
    #pragma unroll
    for (int k = 0; k < 10; ++k) acc = fmaf(s[k] * inv, M[k * 64 + lane], acc);
    const float* xr = fsraw + (long long)w * kx;     // broadcast fp32 self row
    for (int k = 0; k < kx; ++k) acc = fmaf(xr[k], R[k * 64 + lane], acc);
    xout[(long long)w * 64 + lane] = fmaxf(acc, 0.f);
}

// ---------------------------------------------------------------------------
// Merged dual projection (register-tiled mini-GEMM):
//   [y | z] = X1[n,64] @ [Wl2 | Wr2]
// y (cols 0..31) -> BF16 ys/yv scratch (gathered by the other side's gc2);
// z (cols 32..63) -> fp32, DIRECTLY into d_out (self term; gc2 RMWs it).
__global__ __launch_bounds__(256) void projdual(
        const float* __restrict__ xs1, const float* __restrict__ xv1,
        const float* __restrict__ Wl2sv, const float* __restrict__ Wr2vs,
        const float* __restrict__ Wl2vs, const float* __restrict__ Wr2sv,
        unsigned short* __restrict__ ys16, unsigned short* __restrict__ yv16,
        float* __restrict__ out) {
    __shared__ float sW[64 * 64];
    __shared__ float sX[64 * 65];   // +1 pad: conflict-free column reads
    int b = blockIdx.x, tid = threadIdx.x;
    const float *X, *Wl, *Wr; unsigned short* Y; float* Z; int base, n;
    if (b < PD_S) {
        base = b * 64; n = N_SITE; X = xs1;
        Wl = Wl2sv; Wr = Wr2vs; Y = ys16; Z = out;
    } else {
        base = (b - PD_S) * 64; n = N_VENDOR; X = xv1;
        Wl = Wl2vs; Wr = Wr2sv; Y = yv16; Z = out + (long long)N_SITE * OUT;
    }
    for (int i = tid; i < 4096; i += 256) {
        int k = i >> 6, c = i & 63;
        sW[i] = (c < 32) ? Wl[k * 32 + c] : Wr[k * 32 + (c - 32)];
    }
    for (int i = tid; i < 4096; i += 256) {
        int r = i >> 6, c = i & 63;
        int node = base + r;
        sX[r * 65 + c] = (node < n) ? X[(long long)node * 64 + c] : 0.f;
    }
    __syncthreads();
    int ng = tid >> 4, cg = tid & 15;     // 4-node group, 4-col group
    float acc[4][4] = {};
    for (int k = 0; k < 64; ++k) {
        float4 w4 = *(const float4*)(sW + k * 64 + cg * 4);
        #pragma unroll
        for (int i = 0; i < 4; ++i) {
            float xv = sX[(ng * 4 + i) * 65 + k];
            acc[i][0] = fmaf(xv, w4.x, acc[i][0]);
            acc[i][1] = fmaf(xv, w4.y, acc[i][1]);
            acc[i][2] = fmaf(xv, w4.z, acc[i][2]);
            acc[i][3] = fmaf(xv, w4.w, acc[i][3]);
        }
    }
    #pragma unroll
    for (int i = 0; i < 4; ++i) {
        int node = base + ng * 4 + i;
        if (node >= n) continue;
        if (cg < 8) {
            unsigned p01 = (unsigned)bfr(acc[i][0]) | ((unsigned)bfr(acc[i][1]) << 16);
            unsigned p23 = (unsigned)bfr(acc[i][2]) | ((unsigned)bfr(acc[i][3]) << 16);
            *(uint2*)(Y + (long long)node * 32 + cg * 4) = make_uint2(p01, p23);
        } else {
            *(float4*)(Z + (long long)node * 32 + (cg - 8) * 4) =
                make_float4(acc[i][0], acc[i][1], acc[i][2], acc[i][3]);
        }
    }
}

// ---------------------------------------------------------------------------
// Layer-2 gather helper: 8 edge-groups x 8 lanes; each lane covers 4 bf16
// cols via one uint2 per edge (8 load-instructions per 64B row).
template<typename IdxT>
__device__ __forceinline__ void gather2(const unsigned short* __restrict__ y,
                                        const IdxT* __restrict__ adj,
                                        int lo, int deg, int g, int q,
                                        float& s0, float& s1, float& s2, float& s3) {
    int m = (deg > g) ? ((deg - g + 7) >> 3) : 0;
    const IdxT* ap = adj + lo + g;
    int t = 0;
    for (; t + 2 <= m; t += 2) {
        long long a0 = (long long)ap[8 * t];
        long long a1 = (long long)ap[8 * t + 8];
        uint2 u0 = *(const uint2*)(y + a0 * 32 + 4 * q);
        uint2 u1 = *(const uint2*)(y + a1 * 32 + 4 * q);
        s0 += bflo(u0.x) + bflo(u1.x);
        s1 += bfhi(u0.x) + bfhi(u1.x);
        s2 += bflo(u0.y) + bflo(u1.y);
        s3 += bfhi(u0.y) + bfhi(u1.y);
    }
    if (t < m) {
        long long a0 = (long long)ap[8 * t];
        uint2 u0 = *(const uint2*)(y + a0 * 32 + 4 * q);
        s0 += bflo(u0.x); s1 += bfhi(u0.x);
        s2 += bflo(u0.y); s3 += bfhi(u0.y);
    }
}

// Merged layer-2 combine: out = relu(gather_mean(bf16 y) + b + z) where z was
// pre-written into d_out by projdual. One wave per node.
__global__ __launch_bounds__(256) void gc2all(
        const unsigned short* __restrict__ ys16, const unsigned short* __restrict__ yv16,
        const int* __restrict__ off_s, const unsigned short* __restrict__ adj_s16,
        const int* __restrict__ off_v, const int* __restrict__ adj_v,
        const float* __restrict__ bl2vs, const float* __restrict__ bl2sv,
        float* __restrict__ out) {
    int b = blockIdx.x;
    bool site = (b < SB1);
    const float* bias; const int* off; float* o; int w, n;
    if (site) {          // site outputs gather vendor pre-projections
        w = b * 4 + (threadIdx.x >> 6); n = N_SITE;
        off = off_s; bias = bl2vs; o = out;
    } else {
        w = (b - SB1) * 4 + (threadIdx.x >> 6); n = N_VENDOR;
        off = off_v; bias = bl2sv;
        o = out + (long long)N_SITE * OUT;
    }
    if (w >= n) return;
    int lane = threadIdx.x & 63, g = lane >> 3, q = lane & 7;
    int lo = off[w], hi = off[w + 1], deg = hi - lo;
    float s0 = 0.f, s1 = 0.f, s2 = 0.f, s3 = 0.f;
    if (site) gather2(yv16, adj_s16, lo, deg, g, q, s0, s1, s2, s3);
    else      gather2(ys16, adj_v,   lo, deg, g, q, s0, s1, s2, s3);
    #pragma unroll
    for (int m = 8; m <= 32; m <<= 1) {
        s0 += __shfl_xor(s0, m, 64);
        s1 += __shfl_xor(s1, m, 64);
        s2 += __shfl_xor(s2, m, 64);
        s3 += __shfl_xor(s3, m, 64);
    }
    if (g == 0) {
        float inv = 1.0f / (float)max(deg, 1);
        float4 bz = *(const float4*)(bias + 4 * q);
        long long oi = (long long)w * 32 + 4 * q;
        float4 z = *(const float4*)(o + oi);
        float4 r;
        r.x = fmaxf(fmaf(s0, inv, bz.x + z.x), 0.f);
        r.y = fmaxf(fmaf(s1, inv, bz.y + z.y), 0.f);
        r.z = fmaxf(fmaf(s2, inv, bz.z + z.z), 0.f);
        r.w = fmaxf(fmaf(s3, inv, bz.w + z.w), 0.f);
        *(float4*)(o + oi) = r;
    }
}

// ---------------------------------------------------------------------------
extern "C" void kernel_launch(void* const* d_in, const int* in_sizes, int n_in,
                              void* d_out, int out_size, void* d_ws, size_t ws_size,
                              hipStream_t stream) {
    const float* x_site      = (const float*)d_in[0];
    const float* x_vendor    = (const float*)d_in[1];
    const int*   src         = (const int*)d_in[2];
    const int*   dst         = (const int*)d_in[3];
    const float* W_site_in   = (const float*)d_in[4];
    const float* b_site_in   = (const float*)d_in[5];
    const float* W_vendor_in = (const float*)d_in[6];
    const float* b_vendor_in = (const float*)d_in[7];
    const float* Wl1sv = (const float*)d_in[8];
    const float* bl1sv = (const float*)d_in[9];
    const float* Wr1sv = (const float*)d_in[10];
    const float* Wl1vs = (const float*)d_in[11];
    const float* bl1vs = (const float*)d_in[12];
    const float* Wr1vs = (const float*)d_in[13];
    const float* Wl2sv = (const float*)d_in[14];
    const float* bl2sv = (const float*)d_in[15];
    const float* Wr2sv = (const float*)d_in[16];
    const float* Wl2vs = (const float*)d_in[17];
    const float* bl2vs = (const float*)d_in[18];
    const float* Wr2vs = (const float*)d_in[19];

    // Guard: never write past harness scratch (overrun can kill the container).
    if (ws_size < (size_t)WS_WORDS * 4) return;

    int*   wi  = (int*)d_ws;
    float* wf  = (float*)d_ws;
    float* out = (float*)d_out;

    int* off_v  = wi + I_OFF_V;
    int* off_s  = wi + I_OFF_S;
    int* base_s = wi + I_BASE_S;
    int* base_v = wi + I_BASE_V;
    int* tot    = wi + I_TOT;
    int* adj_v  = wi + I_ADJ_V;
    unsigned short* adj_s16 = (unsigned short*)(wi + I_ADJ_S);
    int* h2s    = wi + A_H2S;     // aliases float region (floats written post-build)
    int* h2v    = wi + A_H2V;
    unsigned* pairs_s = (unsigned*)(wi + A_PAIRS);
    unsigned* pairs_v = pairs_s + NE;
    float* xs1   = wf + F_XS1;
    float* xv1   = wf + F_XV1;
    unsigned short* ys16 = (unsigned short*)(wf + F_Y16);
    unsigned short* yv16 = ys16 + (long long)N_SITE * OUT;
    unsigned short* xsp  = (unsigned short*)(wf + F_PAD);
    unsigned short* xvp  = xsp + (long long)N_SITE * 16;
    float* fused = wf + F_FUSED;

    // zero bucket totals (ws not re-poisoned between replays; zero every call)
    hipMemsetAsync(tot, 0, (size_t)(NBUK_S + NBUK_V) * sizeof(int), stream);

    fuse_weights<<<17, 256, 0, stream>>>(W_site_in, b_site_in, W_vendor_in, b_vendor_in,
                                         Wl1sv, Wr1sv, Wl1vs, Wr1vs, fused);
    padfeat<<<(16 * (N_SITE + N_VENDOR) + 255) / 256, 256, 0, stream>>>(
        x_site, x_vendor, xsp, xvp);

    // --- CSR build: two-level radix, packed 4B pairs, u16 site adjacency ---
    histbk<<<NBLK, 256, 0, stream>>>(src, dst, h2s, h2v, tot);
    basescan<<<1, 512, 0, stream>>>(tot, base_s, base_v);
    cursorize<<<NBUK_S + NBUK_V, 256, 0, stream>>>(h2s, h2v, base_s, base_v);
    scatter_both<<<NBLK, 256, 0, stream>>>(src, dst, h2s, h2v, pairs_s, pairs_v);
    stage2both<<<NBUK_S + NBUK_V, 256, 0, stream>>>(pairs_s, pairs_v, base_s, base_v,
                                                    off_s, off_v, adj_s16, adj_v);

    // --- layer 1: merged fused gather+project+self+relu (both directions) ---
    gc1all<<<SB1 + VB1, 256, 0, stream>>>(xsp, xvp, x_site, x_vendor,
                                          off_s, adj_s16, off_v, adj_v,
                                          fused, bl1vs, bl1sv, xs1, xv1);

    // --- layer 2 pre-projections (bf16) + self terms (fp32 into d_out) ---
    projdual<<<PD_S + PD_V, 256, 0, stream>>>(xs1, xv1, Wl2sv, Wr2vs, Wl2vs, Wr2sv,
                                              ys16, yv16, out);

    // --- layer 2: merged gather+mean+bias+self+relu ---
    gc2all<<<SB1 + VB1, 256, 0, stream>>>(ys16, yv16, off_s, adj_s16, off_v, adj_v,
                                          bl2vs, bl2sv, out);

    (void)in_sizes; (void)n_in; (void)out_size;
}

// Round 9
// 352.213 us; speedup vs baseline: 11.7419x; 1.1203x over previous
//
#include <hip/hip_runtime.h>

// Problem constants
constexpr int N_SITE    = 100000;
constexpr int N_VENDOR  = 20000;
constexpr int NE        = 3200000;
constexpr int SITE_IN   = 10;
constexpr int VENDOR_IN = 9;
constexpr int HID       = 64;
constexpr int OUT       = 32;

// Radix-build parameters
constexpr int NBLK    = 1024;            // pass-1 grid (each block = one chunk)
constexpr int EPB     = NE / NBLK;       // 3125 edges per block
constexpr int SHIFT_S = 8;               // 256 sites per bucket
constexpr int NBUK_S  = (N_SITE + 255) / 256;    // 391
constexpr int SHIFT_V = 7;               // 128 vendors per bucket
constexpr int NBUK_V  = (N_VENDOR + 127) / 128;  // 157

// Merged-launch block ranges
constexpr int SB1  = (N_SITE + 3) / 4;           // 25000 (gc2 site blocks)
constexpr int VB1  = (N_VENDOR + 3) / 4;         // 5000
constexpr int NS_BLK = (N_SITE + 15) / 16;       // 6250 (gc1fused site blocks)
constexpr int NV_BLK = (N_VENDOR + 15) / 16;     // 1250

// ---------------------------------------------------------------------------
// Workspace layout (4-byte words).
constexpr long long I_OFF_V  = 0;                                // [N_VENDOR+1]
constexpr long long I_OFF_S  = I_OFF_V + N_VENDOR + 1;           // [N_SITE+1]
constexpr long long I_BASE_S = I_OFF_S + N_SITE + 1;             // [NBUK_S+1]
constexpr long long I_BASE_V = I_BASE_S + NBUK_S + 1;            // [NBUK_V+1]
constexpr long long I_TOT    = I_BASE_V + NBUK_V + 1;            // [NBUK_S+NBUK_V] zeroed/call
constexpr long long I_ADJ_V  = I_TOT + NBUK_S + NBUK_V;          // [NE] int
constexpr long long I_ADJ_S  = I_ADJ_V + NE;                     // [NE/2] words as u16[NE]
constexpr long long INT_END  = I_ADJ_S + NE;                     // (slot kept NE words)
// Build scratch (h2 cursor tables + packed pairs) aliases the float
// intermediates: floats are only written after the build completes.
constexpr long long A_H2S    = INT_END;                          // [NBLK*NBUK_S]
constexpr long long A_H2V    = A_H2S + (long long)NBLK * NBUK_S; // [NBLK*NBUK_V]
constexpr long long A_PAIRS  = (A_H2V + (long long)NBLK * NBUK_V + 1) & ~1LL;
constexpr long long BUILD_END = A_PAIRS + 2LL * NE;              // pairs_s + pairs_v (u32 each)
// bf16 tail: ys16/yv16 (gc1fused->gc2all) and xsp/xvp (padfeat->gc1fused).
constexpr long long F_Y16    = INT_END + (long long)N_SITE * HID + (long long)N_VENDOR * HID;
constexpr long long F_PAD    = F_Y16 + 2000000;                  // ys16+yv16 = 1.92M words
constexpr long long F_END    = F_Y16 + 3840000;
static_assert(F_PAD + (long long)(N_SITE + N_VENDOR) * 16 / 2 <= F_END, "pads fit");
static_assert(BUILD_END < F_Y16, "pairs below bf16 tail region");
constexpr long long SHARED_END = (BUILD_END > F_END) ? BUILD_END : F_END;
constexpr long long F_FUSED  = SHARED_END;                       // [4352]
constexpr long long WS_WORDS = F_FUSED + 4352;                   // ~72.2 MB

// fused sub-offsets (layer-1 matrices padded to 16 rows; pad rows are ZERO)
constexpr int F_M1SV = 0;      // 16x64  W_site_in@Wl1sv   (rows 10..15 = 0)
constexpr int F_M1VS = 1024;   // 16x64  W_vendor_in@Wl1vs (rows 9..15 = 0)
constexpr int F_R1SV = 2048;   // 16x64  W_vendor_in@Wr1sv
constexpr int F_R1VS = 3072;   // 16x64  W_site_in@Wr1vs
constexpr int F_V1SV = 4096;   // 64     b_site_in@Wl1sv
constexpr int F_V1VS = 4160;   // 64     b_vendor_in@Wl1vs
constexpr int F_r1SV = 4224;   // 64     b_vendor_in@Wr1sv
constexpr int F_r1VS = 4288;   // 64     b_site_in@Wr1vs

// bf16 helpers
__device__ __forceinline__ unsigned short bfr(float f) {   // RNE pack
    unsigned u = __float_as_uint(f);
    return (unsigned short)((u + 0x7FFFu + ((u >> 16) & 1u)) >> 16);
}
__device__ __forceinline__ float bflo(unsigned u) { return __uint_as_float(u << 16); }
__device__ __forceinline__ float bfhi(unsigned u) { return __uint_as_float(u & 0xFFFF0000u); }

// ---------------------------------------------------------------------------
// Fold input projection + layer-1 weights into padded fused matrices.
__global__ __launch_bounds__(256) void fuse_weights(
        const float* __restrict__ Wsi, const float* __restrict__ bsi,
        const float* __restrict__ Wvi, const float* __restrict__ bvi,
        const float* __restrict__ Wl1sv, const float* __restrict__ Wr1sv,
        const float* __restrict__ Wl1vs, const float* __restrict__ Wr1vs,
        float* __restrict__ fused) {
    int idx = blockIdx.x * 256 + threadIdx.x;
    if (idx < 4096) {                       // matrices, m = 0..3 (16x64 each)
        int m = idx >> 10, rem = idx & 1023, r = rem >> 6, c = rem & 63;
        int K = (m == 0 || m == 3) ? SITE_IN : VENDOR_IN;
        const float* A = (m == 0 || m == 3) ? Wsi : Wvi;
        const float* B = (m == 0) ? Wl1sv : (m == 1) ? Wl1vs : (m == 2) ? Wr1sv : Wr1vs;
        float s = 0.f;
        if (r < K)
            for (int j = 0; j < 64; ++j) s = fmaf(A[r * 64 + j], B[j * 64 + c], s);
        fused[idx] = s;
    } else if (idx < 4352) {                // bias vectors
        int m = (idx - 4096) >> 6, c = idx & 63;
        const float* a = (m == 0 || m == 3) ? bsi : bvi;
        const float* B = (m == 0) ? Wl1sv : (m == 1) ? Wl1vs : (m == 2) ? Wr1sv : Wr1vs;
        float s = 0.f;
        for (int j = 0; j < 64; ++j) s = fmaf(a[j], B[j * 64 + c], s);
        fused[idx] = s;
    }
}

// ---------------------------------------------------------------------------
// Pad raw features to 16 bf16/row (32 B, aligned) for vectorized gathers.
__global__ __launch_bounds__(256) void padfeat(const float* __restrict__ x_site,
                                               const float* __restrict__ x_vendor,
                                               unsigned short* __restrict__ xsp,
                                               unsigned short* __restrict__ xvp) {
    int t = blockIdx.x * 256 + threadIdx.x;
    if (t < N_SITE * 16) {
        int i = t >> 4, k = t & 15;
        xsp[t] = bfr(k < SITE_IN ? x_site[i * SITE_IN + k] : 0.f);
    } else {
        t -= N_SITE * 16;
        if (t < N_VENDOR * 16) {
            int i = t >> 4, k = t & 15;
            xvp[t] = bfr(k < VENDOR_IN ? x_vendor[i * VENDOR_IN + k] : 0.f);
        }
    }
}

// ---------------------------------------------------------------------------
// Build K1: per-block LDS bucket histograms for BOTH directions in one edge
// read. Writes private h2 rows (no atomics) + merges bucket totals.
__global__ __launch_bounds__(256) void histbk(const int* __restrict__ src,
                                              const int* __restrict__ dst,
                                              int* __restrict__ h2s,
                                              int* __restrict__ h2v,
                                              int* __restrict__ tot) {
    __shared__ int hs[NBUK_S];
    __shared__ int hv[NBUK_V];
    int blk = blockIdx.x, tid = threadIdx.x;
    for (int i = tid; i < NBUK_S; i += 256) hs[i] = 0;
    for (int i = tid; i < NBUK_V; i += 256) hv[i] = 0;
    __syncthreads();
    int lo = blk * EPB;
    for (int e = lo + tid; e < lo + EPB; e += 256) {
        atomicAdd(&hs[src[e] >> SHIFT_S], 1);
        atomicAdd(&hv[dst[e] >> SHIFT_V], 1);
    }
    __syncthreads();
    for (int i = tid; i < NBUK_S; i += 256) {
        int c = hs[i];
        h2s[(long long)blk * NBUK_S + i] = c;
        if (c) atomicAdd(&tot[i], c);
    }
    for (int i = tid; i < NBUK_V; i += 256) {
        int c = hv[i];
        h2v[(long long)blk * NBUK_V + i] = c;
        if (c) atomicAdd(&tot[NBUK_S + i], c);
    }
}

// Build K2: exclusive scan of bucket totals -> bucket base offsets.
__global__ __launch_bounds__(512) void basescan(const int* __restrict__ tot,
                                                int* __restrict__ base_s,
                                                int* __restrict__ base_v) {
    __shared__ int a[512];
    int tid = threadIdx.x;
    int v = (tid < NBUK_S) ? tot[tid] : 0;
    a[tid] = v; __syncthreads();
    for (int st = 1; st < 512; st <<= 1) {
        int x = (tid >= st) ? a[tid - st] : 0; __syncthreads();
        a[tid] += x; __syncthreads();
    }
    if (tid < NBUK_S) base_s[tid] = a[tid] - v;
    if (tid == 0) base_s[NBUK_S] = NE;
    __syncthreads();
    int w = (tid < NBUK_V) ? tot[NBUK_S + tid] : 0;
    a[tid] = w; __syncthreads();
    for (int st = 1; st < 512; st <<= 1) {
        int x = (tid >= st) ? a[tid - st] : 0; __syncthreads();
        a[tid] += x; __syncthreads();
    }
    if (tid < NBUK_V) base_v[tid] = a[tid] - w;
    if (tid == 0) base_v[NBUK_V] = NE;
}

// Build K3: convert h2 counts into per-(chunk,bucket) write cursors.
__global__ __launch_bounds__(256) void cursorize(int* __restrict__ h2s,
                                                 int* __restrict__ h2v,
                                                 const int* __restrict__ base_s,
                                                 const int* __restrict__ base_v) {
    int b = blockIdx.x, tid = threadIdx.x;
    int* h2; const int* base; int nbuk;
    if (b < NBUK_S) { h2 = h2s; base = base_s; nbuk = NBUK_S; }
    else            { b -= NBUK_S; h2 = h2v; base = base_v; nbuk = NBUK_V; }
    int c[4], loc[4], s = 0;
    #pragma unroll
    for (int i = 0; i < 4; ++i) c[i] = h2[(long long)(tid * 4 + i) * nbuk + b];
    #pragma unroll
    for (int i = 0; i < 4; ++i) { loc[i] = s; s += c[i]; }
    __shared__ int p[256];
    p[tid] = s; __syncthreads();
    for (int st = 1; st < 256; st <<= 1) {
        int x = (tid >= st) ? p[tid - st] : 0; __syncthreads();
        p[tid] += x; __syncthreads();
    }
    int pre = base[b] + (tid ? p[tid - 1] : 0);
    #pragma unroll
    for (int i = 0; i < 4; ++i) h2[(long long)(tid * 4 + i) * nbuk + b] = pre + loc[i];
}

// Build K4: scatter PACKED 4-byte pairs for BOTH directions in one edge read.
// site pair:   (site&255)<<24 | vendor   (vendor < 2^15)
// vendor pair: (vendor&127)<<25 | site   (site < 2^17)
__global__ __launch_bounds__(256) void scatter_both(
        const int* __restrict__ src, const int* __restrict__ dst,
        const int* __restrict__ h2s, const int* __restrict__ h2v,
        unsigned* __restrict__ pairs_s, unsigned* __restrict__ pairs_v) {
    __shared__ int cs[NBUK_S];
    __shared__ int cv[NBUK_V];
    int blk = blockIdx.x, tid = threadIdx.x;
    for (int i = tid; i < NBUK_S; i += 256) cs[i] = h2s[(long long)blk * NBUK_S + i];
    for (int i = tid; i < NBUK_V; i += 256) cv[i] = h2v[(long long)blk * NBUK_V + i];
    __syncthreads();
    int lo = blk * EPB;
    for (int e = lo + tid; e < lo + EPB; e += 256) {
        int s = src[e], d = dst[e];
        int ps = atomicAdd(&cs[s >> SHIFT_S], 1);
        pairs_s[ps] = ((unsigned)(s & 255) << 24) | (unsigned)d;
        int pv = atomicAdd(&cv[d >> SHIFT_V], 1);
        pairs_v[pv] = ((unsigned)(d & 127) << 25) | (unsigned)s;
    }
}

// Build K5: per-bucket counting sort for BOTH directions (grid-split).
__global__ __launch_bounds__(256) void stage2both(
        const unsigned* __restrict__ pairs_s, const unsigned* __restrict__ pairs_v,
        const int* __restrict__ base_s, const int* __restrict__ base_v,
        int* __restrict__ off_s, int* __restrict__ off_v,
        unsigned short* __restrict__ adj_s16, int* __restrict__ adj_v) {
    int b = blockIdx.x, tid = threadIdx.x;
    bool site = (b < NBUK_S);
    const unsigned* pairs; const int* base; int* off;
    int BW, nnode, shloc, lo_node;
    if (site) {
        pairs = pairs_s; base = base_s; off = off_s;
        BW = 256; nnode = N_SITE; shloc = 24; lo_node = b << SHIFT_S;
    } else {
        b -= NBUK_S;
        pairs = pairs_v; base = base_v; off = off_v;
        BW = 128; nnode = N_VENDOR; shloc = 25; lo_node = b << SHIFT_V;
    }
    int p0 = base[b], p1 = base[b + 1];
    __shared__ int deg[256];
    __shared__ int cur[256];
    __shared__ int sc[256];
    if (tid < BW) deg[tid] = 0;
    __syncthreads();
    for (int e = p0 + tid; e < p1; e += 256)
        atomicAdd(&deg[(int)(pairs[e] >> shloc)], 1);
    __syncthreads();
    int d = (tid < BW) ? deg[tid] : 0;
    sc[tid] = d;
    __syncthreads();
    for (int st = 1; st < 256; st <<= 1) {
        int x = (tid >= st) ? sc[tid - st] : 0; __syncthreads();
        sc[tid] += x; __syncthreads();
    }
    int excl = sc[tid] - d;
    if (tid < BW) {
        int node = lo_node + tid;
        if (node < nnode) off[node] = p0 + excl;
        cur[tid] = p0 + excl;
    }
    if (tid == 0) {
        if (site && b == NBUK_S - 1) off_s[N_SITE] = NE;
        if (!site && b == NBUK_V - 1) off_v[N_VENDOR] = NE;
    }
    __syncthreads();
    if (site) {
        for (int e = p0 + tid; e < p1; e += 256) {
            unsigned p = pairs[e];
            int pos = atomicAdd(&cur[(int)(p >> 24)], 1);
            adj_s16[pos] = (unsigned short)p;           // vendor id < 2^15
        }
    } else {
        for (int e = p0 + tid; e < p1; e += 256) {
            unsigned p = pairs[e];
            int pos = atomicAdd(&cur[(int)(p >> 25)], 1);
            adj_v[pos] = (int)(p & 0x1FFFFFFu);         // site id < 2^17
        }
    }
}

// ---------------------------------------------------------------------------
// Layer-1 gather helper: 16 lanes per node.
template<typename IdxT>
__device__ __forceinline__ void gather1(const unsigned short* __restrict__ fp,
                                        const IdxT* __restrict__ adj,
                                        int lo, int hi, int l16, float* s) {
    for (int j = lo + l16; j < hi; j += 16) {
        const unsigned short* row = fp + (long long)adj[j] * 16;
        uint4 q0 = *(const uint4*)row;
        unsigned u4 = *(const unsigned*)(row + 8);
        s[0] += bflo(q0.x); s[1] += bfhi(q0.x);
        s[2] += bflo(q0.y); s[3] += bfhi(q0.y);
        s[4] += bflo(q0.z); s[5] += bfhi(q0.z);
        s[6] += bflo(q0.w); s[7] += bfhi(q0.w);
        s[8] += bflo(u4);   s[9] += bfhi(u4);
    }
}

// Fused layer-1 + layer-2 projection. Block = 256 threads = 16 nodes
// (16 lanes/node). Stage B: gather padded bf16 neighbor rows, 4-step
// butterfly (masks 1..8 stay within the 16-lane group), fused mean-project +
// fp32 self-project + relu -> x1 row into LDS. Stage C: per block,
// [y|z] = x1 @ [Wl2|Wr2] from LDS (W staged once); y -> bf16 ys/yv,
// z -> fp32 directly into d_out (self term; gc2all RMWs it).
__global__ __launch_bounds__(256) void gc1fused(
        const unsigned short* __restrict__ xsp, const unsigned short* __restrict__ xvp,
        const float* __restrict__ xs_raw, const float* __restrict__ xv_raw,
        const int* __restrict__ off_s, const unsigned short* __restrict__ adj_s16,
        const int* __restrict__ off_v, const int* __restrict__ adj_v,
        const float* __restrict__ fused,
        const float* __restrict__ bl1vs, const float* __restrict__ bl1sv,
        const float* __restrict__ Wl2sv, const float* __restrict__ Wr2vs,
        const float* __restrict__ Wl2vs, const float* __restrict__ Wr2sv,
        unsigned short* __restrict__ ys16, unsigned short* __restrict__ yv16,
        float* __restrict__ out) {
    __shared__ float sW[64 * 64];     // [k][c] packed [Wl | Wr]
    __shared__ float sX[16][68];      // x1 rows (pad 4 to break bank patterns)
    int b = blockIdx.x, tid = threadIdx.x;
    bool site = (b < NS_BLK);
    const float *fsraw, *M, *V, *BL, *R, *RV, *Wl, *Wr;
    const int* off;
    unsigned short* Y; float* Z;
    int nodebase, n, kx;
    if (site) {          // site node: aggregate vendor feats, self = site feats
        nodebase = b * 16; n = N_SITE; kx = SITE_IN;
        fsraw = xs_raw; off = off_s;
        M = fused + F_M1VS; V = fused + F_V1VS; BL = bl1vs;
        R = fused + F_R1VS; RV = fused + F_r1VS;
        Wl = Wl2sv; Wr = Wr2vs; Y = ys16; Z = out;
    } else {             // vendor node
        nodebase = (b - NS_BLK) * 16; n = N_VENDOR; kx = VENDOR_IN;
        fsraw = xv_raw; off = off_v;
        M = fused + F_M1SV; V = fused + F_V1SV; BL = bl1sv;
        R = fused + F_R1SV; RV = fused + F_r1SV;
        Wl = Wl2vs; Wr = Wr2sv; Y = yv16; Z = out + (long long)N_SITE * OUT;
    }
    // stage W into LDS
    for (int i = tid; i < 4096; i += 256) {
        int k = i >> 6, c = i & 63;
        sW[i] = (c < 32) ? Wl[k * 32 + c] : Wr[k * 32 + (c - 32)];
    }
    // ---- Stage B: layer-1 for this thread's node (16 lanes/node) ----
    int l16 = tid & 15, nib = tid >> 4;
    int w = nodebase + nib;
    int c0 = l16 * 4;
    if (w < n) {
        int lo = off[w], hi = off[w + 1], deg = hi - lo;
        float s[10];
        #pragma unroll
        for (int k = 0; k < 10; ++k) s[k] = 0.f;
        if (site) gather1(xvp, adj_s16, lo, hi, l16, s);
        else      gather1(xsp, adj_v,   lo, hi, l16, s);
        #pragma unroll
        for (int k = 0; k < 10; ++k) {
            s[k] += __shfl_xor(s[k], 1, 64);
            s[k] += __shfl_xor(s[k], 2, 64);
            s[k] += __shfl_xor(s[k], 4, 64);
            s[k] += __shfl_xor(s[k], 8, 64);
        }
        float inv = 1.0f / (float)max(deg, 1);
        float4 acc = *(const float4*)(BL + c0);
        float4 rv4 = *(const float4*)(RV + c0);
        acc.x += rv4.x; acc.y += rv4.y; acc.z += rv4.z; acc.w += rv4.w;
        if (deg > 0) {
            float4 v4 = *(const float4*)(V + c0);
            acc.x += v4.x; acc.y += v4.y; acc.z += v4.z; acc.w += v4.w;
        }
        #pragma unroll
        for (int k = 0; k < 10; ++k) {
            float m = s[k] * inv;
            float4 m4 = *(const float4*)(M + k * 64 + c0);
            acc.x = fmaf(m, m4.x, acc.x);
            acc.y = fmaf(m, m4.y, acc.y);
            acc.z = fmaf(m, m4.z, acc.z);
            acc.w = fmaf(m, m4.w, acc.w);
        }
        const float* xr = fsraw + (long long)w * kx;   // broadcast fp32 self row
        for (int k = 0; k < kx; ++k) {
            float xv = xr[k];
            float4 r4 = *(const float4*)(R + k * 64 + c0);
            acc.x = fmaf(xv, r4.x, acc.x);
            acc.y = fmaf(xv, r4.y, acc.y);
            acc.z = fmaf(xv, r4.z, acc.z);
            acc.w = fmaf(xv, r4.w, acc.w);
        }
        sX[nib][c0 + 0] = fmaxf(acc.x, 0.f);
        sX[nib][c0 + 1] = fmaxf(acc.y, 0.f);
        sX[nib][c0 + 2] = fmaxf(acc.z, 0.f);
        sX[nib][c0 + 3] = fmaxf(acc.w, 0.f);
    }
    __syncthreads();
    // ---- Stage C: [y|z] = x1 @ [Wl|Wr] for the block's 16 nodes ----
    int n2 = tid >> 4, q = tid & 15;   // node, col-group (cols 4q..4q+3)
    int node = nodebase + n2;
    float4 acc = {0.f, 0.f, 0.f, 0.f};
    const float* xrow = sX[n2];
    #pragma unroll 8
    for (int k = 0; k < 64; ++k) {
        float xv = xrow[k];                       // LDS broadcast per 16 threads
        float4 w4 = *(const float4*)(sW + k * 64 + q * 4);
        acc.x = fmaf(xv, w4.x, acc.x);
        acc.y = fmaf(xv, w4.y, acc.y);
        acc.z = fmaf(xv, w4.z, acc.z);
        acc.w = fmaf(xv, w4.w, acc.w);
    }
    if (node < n) {
        if (q < 8) {
            unsigned p01 = (unsigned)bfr(acc.x) | ((unsigned)bfr(acc.y) << 16);
            unsigned p23 = (unsigned)bfr(acc.z) | ((unsigned)bfr(acc.w) << 16);
            *(uint2*)(Y + (long long)node * 32 + q * 4) = make_uint2(p01, p23);
        } else {
            *(float4*)(Z + (long long)node * 32 + (q - 8) * 4) = acc;
        }
    }
}

// ---------------------------------------------------------------------------
// Layer-2 gather helper: 8 edge-groups x 8 lanes; each lane covers 4 bf16
// cols via one uint2 per edge (8 load-instructions per 64B row).
template<typename IdxT>
__device__ __forceinline__ void gather2(const unsigned short* __restrict__ y,
                                        const IdxT* __restrict__ adj,
                                        int lo, int deg, int g, int q,
                                        float& s0, float& s1, float& s2, float& s3) {
    int m = (deg > g) ? ((deg - g + 7) >> 3) : 0;
    const IdxT* ap = adj + lo + g;
    int t = 0;
    for (; t + 2 <= m; t += 2) {
        long long a0 = (long long)ap[8 * t];
        long long a1 = (long long)ap[8 * t + 8];
        uint2 u0 = *(const uint2*)(y + a0 * 32 + 4 * q);
        uint2 u1 = *(const uint2*)(y + a1 * 32 + 4 * q);
        s0 += bflo(u0.x) + bflo(u1.x);
        s1 += bfhi(u0.x) + bfhi(u1.x);
        s2 += bflo(u0.y) + bflo(u1.y);
        s3 += bfhi(u0.y) + bfhi(u1.y);
    }
    if (t < m) {
        long long a0 = (long long)ap[8 * t];
        uint2 u0 = *(const uint2*)(y + a0 * 32 + 4 * q);
        s0 += bflo(u0.x); s1 += bfhi(u0.x);
        s2 += bflo(u0.y); s3 += bfhi(u0.y);
    }
}

// Merged layer-2 combine: out = relu(gather_mean(bf16 y) + b + z) where z was
// pre-written into d_out by gc1fused. One wave per node.
__global__ __launch_bounds__(256) void gc2all(
        const unsigned short* __restrict__ ys16, const unsigned short* __restrict__ yv16,
        const int* __restrict__ off_s, const unsigned short* __restrict__ adj_s16,
        const int* __restrict__ off_v, const int* __restrict__ adj_v,
        const float* __restrict__ bl2vs, const float* __restrict__ bl2sv,
        float* __restrict__ out) {
    int b = blockIdx.x;
    bool site = (b < SB1);
    const float* bias; const int* off; float* o; int w, n;
    if (site) {          // site outputs gather vendor pre-projections
        w = b * 4 + (threadIdx.x >> 6); n = N_SITE;
        off = off_s; bias = bl2vs; o = out;
    } else {
        w = (b - SB1) * 4 + (threadIdx.x >> 6); n = N_VENDOR;
        off = off_v; bias = bl2sv;
        o = out + (long long)N_SITE * OUT;
    }
    if (w >= n) return;
    int lane = threadIdx.x & 63, g = lane >> 3, q = lane & 7;
    int lo = off[w], hi = off[w + 1], deg = hi - lo;
    float s0 = 0.f, s1 = 0.f, s2 = 0.f, s3 = 0.f;
    if (site) gather2(yv16, adj_s16, lo, deg, g, q, s0, s1, s2, s3);
    else      gather2(ys16, adj_v,   lo, deg, g, q, s0, s1, s2, s3);
    #pragma unroll
    for (int m = 8; m <= 32; m <<= 1) {
        s0 += __shfl_xor(s0, m, 64);
        s1 += __shfl_xor(s1, m, 64);
        s2 += __shfl_xor(s2, m, 64);
        s3 += __shfl_xor(s3, m, 64);
    }
    if (g == 0) {
        float inv = 1.0f / (float)max(deg, 1);
        float4 bz = *(const float4*)(bias + 4 * q);
        long long oi = (long long)w * 32 + 4 * q;
        float4 z = *(const float4*)(o + oi);
        float4 r;
        r.x = fmaxf(fmaf(s0, inv, bz.x + z.x), 0.f);
        r.y = fmaxf(fmaf(s1, inv, bz.y + z.y), 0.f);
        r.z = fmaxf(fmaf(s2, inv, bz.z + z.z), 0.f);
        r.w = fmaxf(fmaf(s3, inv, bz.w + z.w), 0.f);
        *(float4*)(o + oi) = r;
    }
}

// ---------------------------------------------------------------------------
extern "C" void kernel_launch(void* const* d_in, const int* in_sizes, int n_in,
                              void* d_out, int out_size, void* d_ws, size_t ws_size,
                              hipStream_t stream) {
    const float* x_site      = (const float*)d_in[0];
    const float* x_vendor    = (const float*)d_in[1];
    const int*   src         = (const int*)d_in[2];
    const int*   dst         = (const int*)d_in[3];
    const float* W_site_in   = (const float*)d_in[4];
    const float* b_site_in   = (const float*)d_in[5];
    const float* W_vendor_in = (const float*)d_in[6];
    const float* b_vendor_in = (const float*)d_in[7];
    const float* Wl1sv = (const float*)d_in[8];
    const float* bl1sv = (const float*)d_in[9];
    const float* Wr1sv = (const float*)d_in[10];
    const float* Wl1vs = (const float*)d_in[11];
    const float* bl1vs = (const float*)d_in[12];
    const float* Wr1vs = (const float*)d_in[13];
    const float* Wl2sv = (const float*)d_in[14];
    const float* bl2sv = (const float*)d_in[15];
    const float* Wr2sv = (const float*)d_in[16];
    const float* Wl2vs = (const float*)d_in[17];
    const float* bl2vs = (const float*)d_in[18];
    const float* Wr2vs = (const float*)d_in[19];

    // Guard: never write past harness scratch (overrun can kill the container).
    if (ws_size < (size_t)WS_WORDS * 4) return;

    int*   wi  = (int*)d_ws;
    float* wf  = (float*)d_ws;
    float* out = (float*)d_out;

    int* off_v  = wi + I_OFF_V;
    int* off_s  = wi + I_OFF_S;
    int* base_s = wi + I_BASE_S;
    int* base_v = wi + I_BASE_V;
    int* tot    = wi + I_TOT;
    int* adj_v  = wi + I_ADJ_V;
    unsigned short* adj_s16 = (unsigned short*)(wi + I_ADJ_S);
    int* h2s    = wi + A_H2S;     // aliases float region (floats written post-build)
    int* h2v    = wi + A_H2V;
    unsigned* pairs_s = (unsigned*)(wi + A_PAIRS);
    unsigned* pairs_v = pairs_s + NE;
    unsigned short* ys16 = (unsigned short*)(wf + F_Y16);
    unsigned short* yv16 = ys16 + (long long)N_SITE * OUT;
    unsigned short* xsp  = (unsigned short*)(wf + F_PAD);
    unsigned short* xvp  = xsp + (long long)N_SITE * 16;
    float* fused = wf + F_FUSED;

    // zero bucket totals (ws not re-poisoned between replays; zero every call)
    hipMemsetAsync(tot, 0, (size_t)(NBUK_S + NBUK_V) * sizeof(int), stream);

    fuse_weights<<<17, 256, 0, stream>>>(W_site_in, b_site_in, W_vendor_in, b_vendor_in,
                                         Wl1sv, Wr1sv, Wl1vs, Wr1vs, fused);
    padfeat<<<(16 * (N_SITE + N_VENDOR) + 255) / 256, 256, 0, stream>>>(
        x_site, x_vendor, xsp, xvp);

    // --- CSR build: two-level radix, packed 4B pairs, u16 site adjacency ---
    histbk<<<NBLK, 256, 0, stream>>>(src, dst, h2s, h2v, tot);
    basescan<<<1, 512, 0, stream>>>(tot, base_s, base_v);
    cursorize<<<NBUK_S + NBUK_V, 256, 0, stream>>>(h2s, h2v, base_s, base_v);
    scatter_both<<<NBLK, 256, 0, stream>>>(src, dst, h2s, h2v, pairs_s, pairs_v);
    stage2both<<<NBUK_S + NBUK_V, 256, 0, stream>>>(pairs_s, pairs_v, base_s, base_v,
                                                    off_s, off_v, adj_s16, adj_v);

    // --- layer 1 + layer-2 projection, fully fused (both directions) ---
    gc1fused<<<NS_BLK + NV_BLK, 256, 0, stream>>>(
        xsp, xvp, x_site, x_vendor, off_s, adj_s16, off_v, adj_v,
        fused, bl1vs, bl1sv, Wl2sv, Wr2vs, Wl2vs, Wr2sv, ys16, yv16, out);

    // --- layer 2: merged gather+mean+bias+self+relu ---
    gc2all<<<SB1 + VB1, 256, 0, stream>>>(ys16, yv16, off_s, adj_s16, off_v, adj_v,
                                          bl2vs, bl2sv, out);

    (void)in_sizes; (void)n_in; (void)out_size;
}